// Round 1
// baseline (1104.088 us; speedup 1.0000x reference)
//
#include <hip/hip_runtime.h>
#include <math.h>

#define BB 1024
#define LL 34
#define DD 128
#define AA 4096
#define NROWS (BB * LL)   // 34816

#define TM 64
#define TK 64
#define LSTR 132          // LDS row stride in floats (33 float4) — breaks bank cycles
#define LSTR4 33

// ---------------------------------------------------------------- kernel 1
// normalize atoms: one wave per atom, float2 per lane
__global__ __launch_bounds__(256) void k_norm_atoms(const float* __restrict__ atoms,
                                                    float* __restrict__ atoms_n) {
    int wid  = threadIdx.x >> 6;
    int lane = threadIdx.x & 63;
    int a = blockIdx.x * 4 + wid;
    float2 v = ((const float2*)(atoms + a * DD))[lane];
    float s = v.x * v.x + v.y * v.y;
    #pragma unroll
    for (int off = 32; off; off >>= 1) s += __shfl_xor(s, off);
    float n = sqrtf(s);
    float inv = 1.0f / fmaxf(n, 1e-12f);
    float2 o; o.x = v.x * inv; o.y = v.y * inv;
    ((float2*)(atoms_n + a * DD))[lane] = o;
}

// ---------------------------------------------------------------- kernel 2
// argmax over atoms for each embedding row, top-2 tracked, fp64 rescore on near-ties
__device__ double score64(const float* __restrict__ e, const float* __restrict__ a) {
    double dot = 0.0, nn = 0.0;
    for (int d = 0; d < DD; d++) {
        double ad = (double)a[d];
        dot += (double)e[d] * ad;
        nn  += ad * ad;
    }
    double n = sqrt(nn);
    if (n < 1e-12) n = 1e-12;
    return dot / n;
}

__global__ __launch_bounds__(256) void k_argmax(const float* __restrict__ emb,
                                                const float* __restrict__ atoms,
                                                const float* __restrict__ atoms_n,
                                                int* __restrict__ amax) {
    __shared__ __align__(16) float embS[TM * LSTR];
    __shared__ __align__(16) float atomS[TK * LSTR];

    const int tid  = threadIdx.x;
    const int rowg = tid >> 4;     // 0..15  -> rows rowg*4 .. rowg*4+3
    const int ag   = tid & 15;     // 0..15  -> atoms ag, ag+16, ag+32, ag+48
    const int rowbase = blockIdx.x * TM;

    // stage 64 embedding rows (coalesced float4)
    for (int f = tid; f < TM * 32; f += 256) {
        int r = f >> 5, c = f & 31;
        ((float4*)embS)[r * LSTR4 + c] = ((const float4*)emb)[(rowbase + r) * 32 + c];
    }

    float v1[4], v2[4];
    int   i1[4], i2[4];
    #pragma unroll
    for (int i = 0; i < 4; i++) { v1[i] = -1e30f; v2[i] = -1e30f; i1[i] = 0; i2[i] = 0; }

    for (int kb = 0; kb < AA / TK; kb++) {
        __syncthreads();   // protect atomS from previous iteration's readers
        for (int f = tid; f < TK * 32; f += 256) {
            int r = f >> 5, c = f & 31;
            ((float4*)atomS)[r * LSTR4 + c] = ((const float4*)atoms_n)[(kb * TK + r) * 32 + c];
        }
        __syncthreads();   // also covers embS staging on kb==0

        float acc[4][4];
        #pragma unroll
        for (int i = 0; i < 4; i++)
            #pragma unroll
            for (int j = 0; j < 4; j++) acc[i][j] = 0.0f;

        #pragma unroll 4
        for (int dd = 0; dd < 32; dd++) {
            float4 e[4], aa[4];
            #pragma unroll
            for (int i = 0; i < 4; i++)
                e[i] = ((const float4*)embS)[(rowg * 4 + i) * LSTR4 + dd];
            #pragma unroll
            for (int j = 0; j < 4; j++)
                aa[j] = ((const float4*)atomS)[(ag + 16 * j) * LSTR4 + dd];
            #pragma unroll
            for (int i = 0; i < 4; i++)
                #pragma unroll
                for (int j = 0; j < 4; j++)
                    acc[i][j] += e[i].x * aa[j].x + e[i].y * aa[j].y +
                                 e[i].z * aa[j].z + e[i].w * aa[j].w;
        }

        #pragma unroll
        for (int i = 0; i < 4; i++) {
            #pragma unroll
            for (int j = 0; j < 4; j++) {
                float val = acc[i][j];
                int   idx = kb * TK + ag + 16 * j;
                if (val > v1[i]) { v2[i] = v1[i]; i2[i] = i1[i]; v1[i] = val; i1[i] = idx; }
                else if (val > v2[i]) { v2[i] = val; i2[i] = idx; }
            }
        }
    }

    __syncthreads();
    // reuse atomS as reduction buffer: 64 rows x 16 groups, four planes
    float* redV1 = atomS;
    float* redV2 = atomS + 1024;
    int*   redI1 = (int*)(atomS + 2048);
    int*   redI2 = (int*)(atomS + 3072);
    #pragma unroll
    for (int i = 0; i < 4; i++) {
        int row = rowg * 4 + i;
        redV1[row * 16 + ag] = v1[i];
        redV2[row * 16 + ag] = v2[i];
        redI1[row * 16 + ag] = i1[i];
        redI2[row * 16 + ag] = i2[i];
    }
    __syncthreads();

    if (tid < TM) {
        int row = tid;
        float bv1 = -1e30f, bv2 = -1e30f;
        int   bi1 = 0, bi2 = 0;
        for (int g = 0; g < 16; g++) {
            float w1 = redV1[row * 16 + g], w2 = redV2[row * 16 + g];
            int   j1 = redI1[row * 16 + g], j2 = redI2[row * 16 + g];
            if (w1 > bv1) { bv2 = bv1; bi2 = bi1; bv1 = w1; bi1 = j1; }
            else if (w1 > bv2) { bv2 = w1; bi2 = j1; }
            if (w2 > bv2) { bv2 = w2; bi2 = j2; }
        }
        int winner = bi1;
        if (bv1 - bv2 < 1e-4f) {
            const float* e = emb + (size_t)(rowbase + row) * DD;
            double s1 = score64(e, atoms + (size_t)bi1 * DD);
            double s2 = score64(e, atoms + (size_t)bi2 * DD);
            if (s2 > s1) winner = bi2;
        }
        amax[rowbase + row] = winner;
    }
}

// ---------------------------------------------------------------- kernel 3
// per-b: gather assoc, att = assoc_flat @ W + b, obj = normalize(att @ assoc)
__global__ __launch_bounds__(256) void k_epilogue(const float* __restrict__ atoms_n,
                                                  const int* __restrict__ amax,
                                                  const float* __restrict__ W,
                                                  const float* __restrict__ b_att,
                                                  float* __restrict__ out) {
    __shared__ __align__(16) float assoc[LL * DD];   // 17408 B
    __shared__ int   idxS[LL];
    __shared__ float attS[LL];
    __shared__ float wsum[4][LL];
    __shared__ float sqw[4];

    const int b = blockIdx.x, tid = threadIdx.x;
    const int wid = tid >> 6, lane = tid & 63;

    if (tid < LL) idxS[tid] = amax[b * LL + tid];
    __syncthreads();

    for (int idx = tid; idx < LL * DD; idx += 256) {
        int l = idx >> 7, d = idx & 127;
        assoc[idx] = atoms_n[(size_t)idxS[l] * DD + d];
    }
    __syncthreads();

    float part[LL];
    #pragma unroll
    for (int j = 0; j < LL; j++) part[j] = 0.0f;
    for (int idx = tid; idx < LL * DD; idx += 256) {
        float v = assoc[idx];
        const float* wr = W + (size_t)idx * LL;
        #pragma unroll
        for (int j = 0; j < LL; j++) part[j] = fmaf(v, wr[j], part[j]);
    }
    #pragma unroll
    for (int off = 32; off; off >>= 1) {
        #pragma unroll
        for (int j = 0; j < LL; j++) part[j] += __shfl_down(part[j], off);
    }
    if (lane == 0) {
        #pragma unroll
        for (int j = 0; j < LL; j++) wsum[wid][j] = part[j];
    }
    __syncthreads();
    if (tid < LL)
        attS[tid] = b_att[tid] + wsum[0][tid] + wsum[1][tid] + wsum[2][tid] + wsum[3][tid];
    __syncthreads();

    float o = 0.0f;
    if (tid < DD) {
        #pragma unroll
        for (int l = 0; l < LL; l++) o = fmaf(attS[l], assoc[l * DD + tid], o);
    }
    float sq = (tid < DD) ? o * o : 0.0f;
    #pragma unroll
    for (int off = 32; off; off >>= 1) sq += __shfl_xor(sq, off);
    if (lane == 0) sqw[wid] = sq;
    __syncthreads();
    float tot = sqw[0] + sqw[1] + sqw[2] + sqw[3];
    float n = sqrtf(tot);
    float inv = 1.0f / fmaxf(n, 1e-12f);
    if (tid < DD) out[(size_t)b * DD + tid] = o * inv;
}

// ---------------------------------------------------------------- launcher
extern "C" void kernel_launch(void* const* d_in, const int* in_sizes, int n_in,
                              void* d_out, int out_size, void* d_ws, size_t ws_size,
                              hipStream_t stream) {
    const float* emb   = (const float*)d_in[0];   // (B, L, D)
    const float* atoms = (const float*)d_in[1];   // (A, D)
    const float* W     = (const float*)d_in[2];   // (L*D, 34)
    const float* b_att = (const float*)d_in[3];   // (34,)
    float* out = (float*)d_out;

    float* atoms_n = (float*)d_ws;                                   // A*D floats = 2 MB
    int*   amax    = (int*)((char*)d_ws + (size_t)AA * DD * sizeof(float)); // NROWS ints

    k_norm_atoms<<<AA / 4, 256, 0, stream>>>(atoms, atoms_n);
    k_argmax<<<NROWS / TM, 256, 0, stream>>>(emb, atoms, atoms_n, amax);
    k_epilogue<<<BB, 256, 0, stream>>>(atoms_n, amax, W, b_att, out);
}

// Round 2
// 455.805 us; speedup vs baseline: 2.4223x; 2.4223x over previous
//
#include <hip/hip_runtime.h>
#include <math.h>

#define BB 1024
#define LL 34
#define DD 128
#define AA 4096
#define NROWS (BB * LL)        // 34816
#define RTILES (NROWS / 16)    // 2176 row tiles
#define ATILES (AA / 16)       // 256 atom tiles
#define NSPLIT 4
#define TAU 5e-4f

typedef short bf16x8 __attribute__((ext_vector_type(8)));
typedef float f32x4  __attribute__((ext_vector_type(4)));

// ---- ws layout (bytes) ----
#define OFF_ATOMSN   0u
#define OFF_EMBA_HI  (2097152u)
#define OFF_EMBA_LO  (OFF_EMBA_HI + 8912896u)
#define OFF_ATOMB_HI (OFF_EMBA_LO + 8912896u)
#define OFF_ATOMB_LO (OFF_ATOMB_HI + 1048576u)
#define OFF_PV1      (OFF_ATOMB_LO + 1048576u)
#define OFF_PV2      (OFF_PV1 + 557056u)
#define OFF_PI1      (OFF_PV2 + 557056u)
#define OFF_AMAX     (OFF_PI1 + 557056u)
#define OFF_INVN64   (OFF_AMAX + 139264u)
#define OFF_FLAGCNT  (OFF_INVN64 + 32768u)
#define OFF_FLAGROWS (OFF_FLAGCNT + 256u)

__device__ __forceinline__ unsigned bf16_rne_bits(float x) {
    unsigned u = __float_as_uint(x);
    unsigned r = (u + 0x7FFFu + ((u >> 16) & 1u)) & 0xFFFF0000u;
    return r;
}

// ---------------------------------------------------------------- k_norm_atoms
// atoms_n (fp32) + fp64 inverse norms; zero flag counter
__global__ __launch_bounds__(256) void k_norm_atoms(const float* __restrict__ atoms,
                                                    float* __restrict__ atoms_n,
                                                    double* __restrict__ invn64,
                                                    int* __restrict__ flagCnt) {
    if (blockIdx.x == 0 && threadIdx.x == 0) *flagCnt = 0;
    int wid  = threadIdx.x >> 6;
    int lane = threadIdx.x & 63;
    int a = blockIdx.x * 4 + wid;
    float2 v = ((const float2*)(atoms + a * DD))[lane];
    double s = (double)v.x * v.x + (double)v.y * v.y;
    #pragma unroll
    for (int off = 32; off; off >>= 1) s += __shfl_xor(s, off);
    double n = sqrt(s);
    if (n < 1e-12) n = 1e-12;
    double inv = 1.0 / n;
    float invf = (float)inv;
    float2 o; o.x = v.x * invf; o.y = v.y * invf;
    ((float2*)(atoms_n + a * DD))[lane] = o;
    if (lane == 0) invn64[a] = inv;
}

// ---------------------------------------------------------------- k_prep
// swizzle emb and atoms_n into MFMA-fragment-linear hi/lo bf16 arrays.
// frag element (tile, ks, lane, j):  src[tile*16 + (lane&15)][(lane>>4)*8 + ks*32 + j]
__global__ __launch_bounds__(256) void k_prep(const float* __restrict__ emb,
                                              const float* __restrict__ atoms_n,
                                              uint4* __restrict__ embA_hi,
                                              uint4* __restrict__ embA_lo,
                                              uint4* __restrict__ atomB_hi,
                                              uint4* __restrict__ atomB_lo) {
    int bid = blockIdx.x;
    const float* src;
    uint4 *dh, *dl;
    int tile;
    if (bid < RTILES) { tile = bid; src = emb; dh = embA_hi; dl = embA_lo; }
    else { tile = bid - RTILES; src = atoms_n; dh = atomB_hi; dl = atomB_lo; }

    int ks = threadIdx.x >> 6, l = threadIdx.x & 63;
    int m = l & 15, koff = ((l >> 4) << 3) + (ks << 5);
    const float* p = src + (size_t)(tile * 16 + m) * DD + koff;
    float4 f0 = ((const float4*)p)[0];
    float4 f1 = ((const float4*)p)[1];
    float xs[8] = {f0.x, f0.y, f0.z, f0.w, f1.x, f1.y, f1.z, f1.w};
    unsigned h[8], lo[8];
    #pragma unroll
    for (int j = 0; j < 8; j++) {
        unsigned hb = bf16_rne_bits(xs[j]);
        h[j] = hb >> 16;
        float res = xs[j] - __uint_as_float(hb);
        lo[j] = bf16_rne_bits(res) >> 16;
    }
    uint4 ph, pl;
    ph.x = h[0] | (h[1] << 16);  ph.y = h[2] | (h[3] << 16);
    ph.z = h[4] | (h[5] << 16);  ph.w = h[6] | (h[7] << 16);
    pl.x = lo[0] | (lo[1] << 16); pl.y = lo[2] | (lo[3] << 16);
    pl.z = lo[4] | (lo[5] << 16); pl.w = lo[6] | (lo[7] << 16);
    size_t idx = (size_t)(tile * 4 + ks) * 64 + l;
    dh[idx] = ph;
    dl[idx] = pl;
}

// ---------------------------------------------------------------- k_score
// split-bf16 MFMA scoring + fused per-row top-2 (value) / top-1 (index)
__global__ __launch_bounds__(256, 2) void k_score(const bf16x8* __restrict__ embA_hi,
                                                  const bf16x8* __restrict__ embA_lo,
                                                  const bf16x8* __restrict__ atomB_hi,
                                                  const bf16x8* __restrict__ atomB_lo,
                                                  float* __restrict__ pv1,
                                                  float* __restrict__ pv2,
                                                  int* __restrict__ pi1) {
    const int tid = threadIdx.x;
    const int w = tid >> 6, l = tid & 63;
    const int rb = blockIdx.x >> 2, sp = blockIdx.x & 3;
    const int rt0 = rb * 8 + w * 2;

    bf16x8 a_hi[2][4], a_lo[2][4];
    #pragma unroll
    for (int f = 0; f < 2; f++)
        #pragma unroll
        for (int ks = 0; ks < 4; ks++) {
            size_t idx = (size_t)((rt0 + f) * 4 + ks) * 64 + l;
            a_hi[f][ks] = embA_hi[idx];
            a_lo[f][ks] = embA_lo[idx];
        }

    float v1[8], v2[8];
    int i1[8];
    #pragma unroll
    for (int s = 0; s < 8; s++) { v1[s] = -3e38f; v2[s] = -3e38f; i1[s] = 0; }

    const int t0 = sp * (ATILES / NSPLIT);
    for (int t = t0; t < t0 + ATILES / NSPLIT; t++) {
        bf16x8 bh[4], bl[4];
        #pragma unroll
        for (int ks = 0; ks < 4; ks++) {
            size_t bidx = (size_t)t * 256 + ks * 64 + l;
            bh[ks] = atomB_hi[bidx];
            bl[ks] = atomB_lo[bidx];
        }
        f32x4 acc[2];
        acc[0] = (f32x4){0.f, 0.f, 0.f, 0.f};
        acc[1] = (f32x4){0.f, 0.f, 0.f, 0.f};
        #pragma unroll
        for (int ks = 0; ks < 4; ks++) {
            acc[0] = __builtin_amdgcn_mfma_f32_16x16x32_bf16(a_lo[0][ks], bh[ks], acc[0], 0, 0, 0);
            acc[0] = __builtin_amdgcn_mfma_f32_16x16x32_bf16(a_hi[0][ks], bl[ks], acc[0], 0, 0, 0);
            acc[0] = __builtin_amdgcn_mfma_f32_16x16x32_bf16(a_hi[0][ks], bh[ks], acc[0], 0, 0, 0);
            acc[1] = __builtin_amdgcn_mfma_f32_16x16x32_bf16(a_lo[1][ks], bh[ks], acc[1], 0, 0, 0);
            acc[1] = __builtin_amdgcn_mfma_f32_16x16x32_bf16(a_hi[1][ks], bl[ks], acc[1], 0, 0, 0);
            acc[1] = __builtin_amdgcn_mfma_f32_16x16x32_bf16(a_hi[1][ks], bh[ks], acc[1], 0, 0, 0);
        }
        const int aidx = t * 16 + (l & 15);
        #pragma unroll
        for (int f = 0; f < 2; f++)
            #pragma unroll
            for (int r = 0; r < 4; r++) {
                int s = f * 4 + r;
                float x = acc[f][r];
                v2[s] = fmaxf(v2[s], fminf(x, v1[s]));
                i1[s] = (x > v1[s]) ? aidx : i1[s];
                v1[s] = fmaxf(v1[s], x);
            }
    }

    // butterfly across the 16 lanes of each quad-group (same rows, different atoms)
    #pragma unroll
    for (int m = 1; m <= 8; m <<= 1) {
        #pragma unroll
        for (int s = 0; s < 8; s++) {
            float ov1 = __shfl_xor(v1[s], m);
            float ov2 = __shfl_xor(v2[s], m);
            int   oi1 = __shfl_xor(i1[s], m);
            float nv2 = fmaxf(fminf(v1[s], ov1), fmaxf(v2[s], ov2));
            i1[s] = (ov1 > v1[s]) ? oi1 : i1[s];
            v1[s] = fmaxf(v1[s], ov1);
            v2[s] = nv2;
        }
    }

    if ((l & 15) == 0) {
        int q = l >> 4;
        #pragma unroll
        for (int f = 0; f < 2; f++)
            #pragma unroll
            for (int r = 0; r < 4; r++) {
                int s = f * 4 + r;
                int row = rb * 128 + w * 32 + f * 16 + q * 4 + r;
                size_t o = (size_t)sp * NROWS + row;
                pv1[o] = v1[s];
                pv2[o] = v2[s];
                pi1[o] = i1[s];
            }
    }
}

// ---------------------------------------------------------------- k_merge
__global__ __launch_bounds__(256) void k_merge(const float* __restrict__ pv1,
                                               const float* __restrict__ pv2,
                                               const int* __restrict__ pi1,
                                               int* __restrict__ amax,
                                               int* __restrict__ flagCnt,
                                               int* __restrict__ flagRows) {
    int r = blockIdx.x * 256 + threadIdx.x;
    float V1 = -3e38f, V2 = -3e38f;
    int I1 = 0;
    #pragma unroll
    for (int sp = 0; sp < NSPLIT; sp++) {
        size_t o = (size_t)sp * NROWS + r;
        float a1 = pv1[o], a2 = pv2[o];
        int   ai = pi1[o];
        float nV2 = fmaxf(fminf(V1, a1), fmaxf(V2, a2));
        I1 = (a1 > V1) ? ai : I1;
        V1 = fmaxf(V1, a1);
        V2 = nV2;
    }
    amax[r] = I1;
    if (V1 - V2 < TAU) {
        int k = atomicAdd(flagCnt, 1);
        flagRows[k] = r;
    }
}

// ---------------------------------------------------------------- k_cleanup
// fp64 full rescan of flagged rows (exact truth, matches round-1-validated path)
__global__ __launch_bounds__(256) void k_cleanup(const float* __restrict__ emb,
                                                 const float* __restrict__ atoms,
                                                 const double* __restrict__ invn64,
                                                 const int* __restrict__ flagCnt,
                                                 const int* __restrict__ flagRows,
                                                 int* __restrict__ amax) {
    __shared__ double eS[DD];
    __shared__ double bvS[4];
    __shared__ int    biS[4];
    int cnt = *flagCnt;
    int tid = threadIdx.x, w = tid >> 6, l = tid & 63;

    for (int fi = blockIdx.x; fi < cnt; fi += gridDim.x) {
        int row = flagRows[fi];
        __syncthreads();
        if (tid < DD) eS[tid] = (double)emb[(size_t)row * DD + tid];
        __syncthreads();

        double bv = -1e300;
        int bi = 0;
        for (int a = w * (AA / 4) + l; a < (w + 1) * (AA / 4); a += 64) {
            const float4* ar = (const float4*)(atoms + (size_t)a * DD);
            double dot = 0.0;
            #pragma unroll 4
            for (int k = 0; k < 32; k++) {
                float4 v = ar[k];
                dot += eS[4*k+0] * (double)v.x + eS[4*k+1] * (double)v.y +
                       eS[4*k+2] * (double)v.z + eS[4*k+3] * (double)v.w;
            }
            double sc = dot * invn64[a];
            if (sc > bv || (sc == bv && a < bi)) { bv = sc; bi = a; }
        }
        #pragma unroll
        for (int m = 1; m <= 32; m <<= 1) {
            double ov = __shfl_xor(bv, m);
            int    oi = __shfl_xor(bi, m);
            if (ov > bv || (ov == bv && oi < bi)) { bv = ov; bi = oi; }
        }
        if (l == 0) { bvS[w] = bv; biS[w] = bi; }
        __syncthreads();
        if (tid == 0) {
            double BV = bvS[0]; int BI = biS[0];
            for (int q = 1; q < 4; q++) {
                if (bvS[q] > BV || (bvS[q] == BV && biS[q] < BI)) { BV = bvS[q]; BI = biS[q]; }
            }
            amax[row] = BI;
        }
    }
}

// ---------------------------------------------------------------- k_epilogue
__global__ __launch_bounds__(256) void k_epilogue(const float* __restrict__ atoms_n,
                                                  const int* __restrict__ amax,
                                                  const float* __restrict__ W,
                                                  const float* __restrict__ b_att,
                                                  float* __restrict__ out) {
    __shared__ __align__(16) float assoc[LL * DD];
    __shared__ int   idxS[LL];
    __shared__ float attS[LL];
    __shared__ float wsum[4][LL];
    __shared__ float sqw[4];

    const int b = blockIdx.x, tid = threadIdx.x;
    const int wid = tid >> 6, lane = tid & 63;

    if (tid < LL) idxS[tid] = amax[b * LL + tid];
    __syncthreads();

    for (int idx = tid; idx < LL * DD; idx += 256) {
        int l = idx >> 7, d = idx & 127;
        assoc[idx] = atoms_n[(size_t)idxS[l] * DD + d];
    }
    __syncthreads();

    float part[LL];
    #pragma unroll
    for (int j = 0; j < LL; j++) part[j] = 0.0f;
    for (int idx = tid; idx < LL * DD; idx += 256) {
        float v = assoc[idx];
        const float* wr = W + (size_t)idx * LL;
        #pragma unroll
        for (int j = 0; j < LL; j++) part[j] = fmaf(v, wr[j], part[j]);
    }
    #pragma unroll
    for (int off = 32; off; off >>= 1) {
        #pragma unroll
        for (int j = 0; j < LL; j++) part[j] += __shfl_down(part[j], off);
    }
    if (lane == 0) {
        #pragma unroll
        for (int j = 0; j < LL; j++) wsum[wid][j] = part[j];
    }
    __syncthreads();
    if (tid < LL)
        attS[tid] = b_att[tid] + wsum[0][tid] + wsum[1][tid] + wsum[2][tid] + wsum[3][tid];
    __syncthreads();

    float o = 0.0f;
    if (tid < DD) {
        #pragma unroll
        for (int l = 0; l < LL; l++) o = fmaf(attS[l], assoc[l * DD + tid], o);
    }
    float sq = (tid < DD) ? o * o : 0.0f;
    #pragma unroll
    for (int off = 32; off; off >>= 1) sq += __shfl_xor(sq, off);
    if (lane == 0) sqw[wid] = sq;
    __syncthreads();
    float tot = sqw[0] + sqw[1] + sqw[2] + sqw[3];
    float n = sqrtf(tot);
    float inv = 1.0f / fmaxf(n, 1e-12f);
    if (tid < DD) out[(size_t)b * DD + tid] = o * inv;
}

// ---------------------------------------------------------------- launcher
extern "C" void kernel_launch(void* const* d_in, const int* in_sizes, int n_in,
                              void* d_out, int out_size, void* d_ws, size_t ws_size,
                              hipStream_t stream) {
    const float* emb   = (const float*)d_in[0];
    const float* atoms = (const float*)d_in[1];
    const float* W     = (const float*)d_in[2];
    const float* b_att = (const float*)d_in[3];
    float* out = (float*)d_out;

    char* ws = (char*)d_ws;
    float*  atoms_n  = (float*)(ws + OFF_ATOMSN);
    uint4*  embA_hi  = (uint4*)(ws + OFF_EMBA_HI);
    uint4*  embA_lo  = (uint4*)(ws + OFF_EMBA_LO);
    uint4*  atomB_hi = (uint4*)(ws + OFF_ATOMB_HI);
    uint4*  atomB_lo = (uint4*)(ws + OFF_ATOMB_LO);
    float*  pv1      = (float*)(ws + OFF_PV1);
    float*  pv2      = (float*)(ws + OFF_PV2);
    int*    pi1      = (int*)(ws + OFF_PI1);
    int*    amax     = (int*)(ws + OFF_AMAX);
    double* invn64   = (double*)(ws + OFF_INVN64);
    int*    flagCnt  = (int*)(ws + OFF_FLAGCNT);
    int*    flagRows = (int*)(ws + OFF_FLAGROWS);

    k_norm_atoms<<<AA / 4, 256, 0, stream>>>(atoms, atoms_n, invn64, flagCnt);
    k_prep<<<RTILES + ATILES, 256, 0, stream>>>(emb, atoms_n, embA_hi, embA_lo, atomB_hi, atomB_lo);
    k_score<<<(RTILES / 8) * NSPLIT, 256, 0, stream>>>((const bf16x8*)embA_hi, (const bf16x8*)embA_lo,
                                                       (const bf16x8*)atomB_hi, (const bf16x8*)atomB_lo,
                                                       pv1, pv2, pi1);
    k_merge<<<NROWS / 256, 256, 0, stream>>>(pv1, pv2, pi1, amax, flagCnt, flagRows);
    k_cleanup<<<64, 256, 0, stream>>>(emb, atoms, invn64, flagCnt, flagRows, amax);
    k_epilogue<<<BB, 256, 0, stream>>>(atoms_n, amax, W, b_att, out);
}

// Round 3
// 351.202 us; speedup vs baseline: 3.1437x; 1.2978x over previous
//
#include <hip/hip_runtime.h>
#include <math.h>

#define BB 1024
#define LL 34
#define DD 128
#define AA 4096
#define NROWS (BB * LL)        // 34816
#define RTILES (NROWS / 16)    // 2176 row tiles
#define ATILES (AA / 16)       // 256 atom tiles
#define NSPLIT 4
#define TAU 1e-3f

typedef short bf16x8 __attribute__((ext_vector_type(8)));
typedef float f32x4  __attribute__((ext_vector_type(4)));

// ---- ws layout (bytes) ----
#define OFF_ATOMSN   0u
#define OFF_EMBA_HI  (2097152u)
#define OFF_EMBA_LO  (OFF_EMBA_HI + 8912896u)
#define OFF_ATOMB_HI (OFF_EMBA_LO + 8912896u)
#define OFF_ATOMB_LO (OFF_ATOMB_HI + 1048576u)
#define OFF_PV1      (OFF_ATOMB_LO + 1048576u)
#define OFF_PV2      (OFF_PV1 + 557056u)
#define OFF_PI1      (OFF_PV2 + 557056u)
#define OFF_PI2      (OFF_PI1 + 557056u)
#define OFF_AMAX     (OFF_PI2 + 557056u)
#define OFF_INVN64   (OFF_AMAX + 139264u)

__device__ __forceinline__ unsigned bf16_rne_bits(float x) {
    unsigned u = __float_as_uint(x);
    unsigned r = (u + 0x7FFFu + ((u >> 16) & 1u)) & 0xFFFF0000u;
    return r;
}

// ---------------------------------------------------------------- k_norm_atoms
__global__ __launch_bounds__(256) void k_norm_atoms(const float* __restrict__ atoms,
                                                    float* __restrict__ atoms_n,
                                                    double* __restrict__ invn64) {
    int wid  = threadIdx.x >> 6;
    int lane = threadIdx.x & 63;
    int a = blockIdx.x * 4 + wid;
    float2 v = ((const float2*)(atoms + a * DD))[lane];
    double s = (double)v.x * v.x + (double)v.y * v.y;
    #pragma unroll
    for (int off = 32; off; off >>= 1) s += __shfl_xor(s, off);
    double n = sqrt(s);
    if (n < 1e-12) n = 1e-12;
    double inv = 1.0 / n;
    float invf = (float)inv;
    float2 o; o.x = v.x * invf; o.y = v.y * invf;
    ((float2*)(atoms_n + a * DD))[lane] = o;
    if (lane == 0) invn64[a] = inv;
}

// ---------------------------------------------------------------- k_prep
// swizzle emb and atoms_n into MFMA-fragment-linear hi/lo bf16 arrays.
__global__ __launch_bounds__(256) void k_prep(const float* __restrict__ emb,
                                              const float* __restrict__ atoms_n,
                                              uint4* __restrict__ embA_hi,
                                              uint4* __restrict__ embA_lo,
                                              uint4* __restrict__ atomB_hi,
                                              uint4* __restrict__ atomB_lo) {
    int bid = blockIdx.x;
    const float* src;
    uint4 *dh, *dl;
    int tile;
    if (bid < RTILES) { tile = bid; src = emb; dh = embA_hi; dl = embA_lo; }
    else { tile = bid - RTILES; src = atoms_n; dh = atomB_hi; dl = atomB_lo; }

    int ks = threadIdx.x >> 6, l = threadIdx.x & 63;
    int m = l & 15, koff = ((l >> 4) << 3) + (ks << 5);
    const float* p = src + (size_t)(tile * 16 + m) * DD + koff;
    float4 f0 = ((const float4*)p)[0];
    float4 f1 = ((const float4*)p)[1];
    float xs[8] = {f0.x, f0.y, f0.z, f0.w, f1.x, f1.y, f1.z, f1.w};
    unsigned h[8], lo[8];
    #pragma unroll
    for (int j = 0; j < 8; j++) {
        unsigned hb = bf16_rne_bits(xs[j]);
        h[j] = hb >> 16;
        float res = xs[j] - __uint_as_float(hb);
        lo[j] = bf16_rne_bits(res) >> 16;
    }
    uint4 ph, pl;
    ph.x = h[0] | (h[1] << 16);  ph.y = h[2] | (h[3] << 16);
    ph.z = h[4] | (h[5] << 16);  ph.w = h[6] | (h[7] << 16);
    pl.x = lo[0] | (lo[1] << 16); pl.y = lo[2] | (lo[3] << 16);
    pl.z = lo[4] | (lo[5] << 16); pl.w = lo[6] | (lo[7] << 16);
    size_t idx = (size_t)(tile * 4 + ks) * 64 + l;
    dh[idx] = ph;
    dl[idx] = pl;
}

// ---------------------------------------------------------------- k_score
// split-bf16 MFMA scoring + fused per-row top-2 (value AND index)
__global__ __launch_bounds__(256, 2) void k_score(const bf16x8* __restrict__ embA_hi,
                                                  const bf16x8* __restrict__ embA_lo,
                                                  const bf16x8* __restrict__ atomB_hi,
                                                  const bf16x8* __restrict__ atomB_lo,
                                                  float* __restrict__ pv1,
                                                  float* __restrict__ pv2,
                                                  int* __restrict__ pi1,
                                                  int* __restrict__ pi2) {
    const int tid = threadIdx.x;
    const int w = tid >> 6, l = tid & 63;
    const int rb = blockIdx.x >> 2, sp = blockIdx.x & 3;
    const int rt0 = rb * 8 + w * 2;

    bf16x8 a_hi[2][4], a_lo[2][4];
    #pragma unroll
    for (int f = 0; f < 2; f++)
        #pragma unroll
        for (int ks = 0; ks < 4; ks++) {
            size_t idx = (size_t)((rt0 + f) * 4 + ks) * 64 + l;
            a_hi[f][ks] = embA_hi[idx];
            a_lo[f][ks] = embA_lo[idx];
        }

    float v1[8], v2[8];
    int i1[8], i2[8];
    #pragma unroll
    for (int s = 0; s < 8; s++) { v1[s] = -3e38f; v2[s] = -3e38f; i1[s] = 0; i2[s] = 0; }

    const int t0 = sp * (ATILES / NSPLIT);
    for (int t = t0; t < t0 + ATILES / NSPLIT; t++) {
        bf16x8 bh[4], bl[4];
        #pragma unroll
        for (int ks = 0; ks < 4; ks++) {
            size_t bidx = (size_t)t * 256 + ks * 64 + l;
            bh[ks] = atomB_hi[bidx];
            bl[ks] = atomB_lo[bidx];
        }
        f32x4 acc[2];
        acc[0] = (f32x4){0.f, 0.f, 0.f, 0.f};
        acc[1] = (f32x4){0.f, 0.f, 0.f, 0.f};
        #pragma unroll
        for (int ks = 0; ks < 4; ks++) {
            acc[0] = __builtin_amdgcn_mfma_f32_16x16x32_bf16(a_lo[0][ks], bh[ks], acc[0], 0, 0, 0);
            acc[0] = __builtin_amdgcn_mfma_f32_16x16x32_bf16(a_hi[0][ks], bl[ks], acc[0], 0, 0, 0);
            acc[0] = __builtin_amdgcn_mfma_f32_16x16x32_bf16(a_hi[0][ks], bh[ks], acc[0], 0, 0, 0);
            acc[1] = __builtin_amdgcn_mfma_f32_16x16x32_bf16(a_lo[1][ks], bh[ks], acc[1], 0, 0, 0);
            acc[1] = __builtin_amdgcn_mfma_f32_16x16x32_bf16(a_hi[1][ks], bl[ks], acc[1], 0, 0, 0);
            acc[1] = __builtin_amdgcn_mfma_f32_16x16x32_bf16(a_hi[1][ks], bh[ks], acc[1], 0, 0, 0);
        }
        const int aidx = t * 16 + (l & 15);
        #pragma unroll
        for (int f = 0; f < 2; f++)
            #pragma unroll
            for (int r = 0; r < 4; r++) {
                int s = f * 4 + r;
                float x = acc[f][r];
                bool gt1 = x > v1[s];
                bool gt2 = x > v2[s];
                i2[s] = gt1 ? i1[s] : (gt2 ? aidx : i2[s]);
                v2[s] = gt1 ? v1[s] : (gt2 ? x : v2[s]);
                i1[s] = gt1 ? aidx : i1[s];
                v1[s] = gt1 ? x : v1[s];
            }
    }

    // butterfly across the 16 lanes of each quad-group (disjoint atom sets)
    #pragma unroll
    for (int m = 1; m <= 8; m <<= 1) {
        #pragma unroll
        for (int s = 0; s < 8; s++) {
            float ov1 = __shfl_xor(v1[s], m);
            float ov2 = __shfl_xor(v2[s], m);
            int   oi1 = __shfl_xor(i1[s], m);
            int   oi2 = __shfl_xor(i2[s], m);
            bool sel = ov1 > v1[s];
            float lv  = sel ? v1[s] : ov1;   // loser's top-1
            int   li  = sel ? i1[s] : oi1;
            float wv2 = sel ? ov2 : v2[s];   // winner's top-2
            int   wi2 = sel ? oi2 : i2[s];
            v1[s] = sel ? ov1 : v1[s];
            i1[s] = sel ? oi1 : i1[s];
            bool s2 = lv > wv2;
            v2[s] = s2 ? lv : wv2;
            i2[s] = s2 ? li : wi2;
        }
    }

    if ((l & 15) == 0) {
        int q = l >> 4;
        #pragma unroll
        for (int f = 0; f < 2; f++)
            #pragma unroll
            for (int r = 0; r < 4; r++) {
                int s = f * 4 + r;
                int row = rb * 128 + w * 32 + f * 16 + q * 4 + r;
                size_t o = (size_t)sp * NROWS + row;
                pv1[o] = v1[s];
                pv2[o] = v2[s];
                pi1[o] = i1[s];
                pi2[o] = i2[s];
            }
    }
}

// ---------------------------------------------------------------- k_merge
// merge the 4 split top-2 lists; fp64 rescore of top-2 on near-tie (fused)
__global__ __launch_bounds__(256) void k_merge(const float* __restrict__ pv1,
                                               const float* __restrict__ pv2,
                                               const int* __restrict__ pi1,
                                               const int* __restrict__ pi2,
                                               const float* __restrict__ emb,
                                               const float* __restrict__ atoms,
                                               const double* __restrict__ invn64,
                                               int* __restrict__ amax) {
    int r = blockIdx.x * 256 + threadIdx.x;
    float V1 = -3e38f, V2 = -3e38f;
    int I1 = 0, I2 = 0;
    #pragma unroll
    for (int sp = 0; sp < NSPLIT; sp++) {
        size_t o = (size_t)sp * NROWS + r;
        float a1 = pv1[o], a2 = pv2[o];
        int   j1 = pi1[o], j2 = pi2[o];
        bool sel = a1 > V1;
        float lv  = sel ? V1 : a1;
        int   li  = sel ? I1 : j1;
        float wv2 = sel ? a2 : V2;
        int   wi2 = sel ? j2 : I2;
        V1 = sel ? a1 : V1;
        I1 = sel ? j1 : I1;
        bool s2 = lv > wv2;
        V2 = s2 ? lv : wv2;
        I2 = s2 ? li : wi2;
    }
    int winner = I1;
    if (V1 - V2 < TAU) {
        const float4* e4 = (const float4*)(emb + (size_t)r * DD);
        const float4* a4 = (const float4*)(atoms + (size_t)I1 * DD);
        const float4* b4 = (const float4*)(atoms + (size_t)I2 * DD);
        double d1 = 0.0, d2 = 0.0;
        #pragma unroll 8
        for (int k = 0; k < 32; k++) {
            float4 ev = e4[k], av = a4[k], bv = b4[k];
            d1 += (double)ev.x * av.x + (double)ev.y * av.y +
                  (double)ev.z * av.z + (double)ev.w * av.w;
            d2 += (double)ev.x * bv.x + (double)ev.y * bv.y +
                  (double)ev.z * bv.z + (double)ev.w * bv.w;
        }
        double s1 = d1 * invn64[I1];
        double s2v = d2 * invn64[I2];
        if (s2v > s1 || (s2v == s1 && I2 < I1)) winner = I2;
    }
    amax[r] = winner;
}

// ---------------------------------------------------------------- k_epilogue
__global__ __launch_bounds__(256) void k_epilogue(const float* __restrict__ atoms_n,
                                                  const int* __restrict__ amax,
                                                  const float* __restrict__ W,
                                                  const float* __restrict__ b_att,
                                                  float* __restrict__ out) {
    __shared__ __align__(16) float assoc[LL * DD];
    __shared__ int   idxS[LL];
    __shared__ float attS[LL];
    __shared__ float wsum[4][LL];
    __shared__ float sqw[4];

    const int b = blockIdx.x, tid = threadIdx.x;
    const int wid = tid >> 6, lane = tid & 63;

    if (tid < LL) idxS[tid] = amax[b * LL + tid];
    __syncthreads();

    for (int idx = tid; idx < LL * DD; idx += 256) {
        int l = idx >> 7, d = idx & 127;
        assoc[idx] = atoms_n[(size_t)idxS[l] * DD + d];
    }
    __syncthreads();

    float part[LL];
    #pragma unroll
    for (int j = 0; j < LL; j++) part[j] = 0.0f;
    for (int idx = tid; idx < LL * DD; idx += 256) {
        float v = assoc[idx];
        const float* wr = W + (size_t)idx * LL;
        #pragma unroll
        for (int j = 0; j < LL; j++) part[j] = fmaf(v, wr[j], part[j]);
    }
    #pragma unroll
    for (int off = 32; off; off >>= 1) {
        #pragma unroll
        for (int j = 0; j < LL; j++) part[j] += __shfl_down(part[j], off);
    }
    if (lane == 0) {
        #pragma unroll
        for (int j = 0; j < LL; j++) wsum[wid][j] = part[j];
    }
    __syncthreads();
    if (tid < LL)
        attS[tid] = b_att[tid] + wsum[0][tid] + wsum[1][tid] + wsum[2][tid] + wsum[3][tid];
    __syncthreads();

    float o = 0.0f;
    if (tid < DD) {
        #pragma unroll
        for (int l = 0; l < LL; l++) o = fmaf(attS[l], assoc[l * DD + tid], o);
    }
    float sq = (tid < DD) ? o * o : 0.0f;
    #pragma unroll
    for (int off = 32; off; off >>= 1) sq += __shfl_xor(sq, off);
    if (lane == 0) sqw[wid] = sq;
    __syncthreads();
    float tot = sqw[0] + sqw[1] + sqw[2] + sqw[3];
    float n = sqrtf(tot);
    float inv = 1.0f / fmaxf(n, 1e-12f);
    if (tid < DD) out[(size_t)b * DD + tid] = o * inv;
}

// ---------------------------------------------------------------- launcher
extern "C" void kernel_launch(void* const* d_in, const int* in_sizes, int n_in,
                              void* d_out, int out_size, void* d_ws, size_t ws_size,
                              hipStream_t stream) {
    const float* emb   = (const float*)d_in[0];
    const float* atoms = (const float*)d_in[1];
    const float* W     = (const float*)d_in[2];
    const float* b_att = (const float*)d_in[3];
    float* out = (float*)d_out;

    char* ws = (char*)d_ws;
    float*  atoms_n  = (float*)(ws + OFF_ATOMSN);
    uint4*  embA_hi  = (uint4*)(ws + OFF_EMBA_HI);
    uint4*  embA_lo  = (uint4*)(ws + OFF_EMBA_LO);
    uint4*  atomB_hi = (uint4*)(ws + OFF_ATOMB_HI);
    uint4*  atomB_lo = (uint4*)(ws + OFF_ATOMB_LO);
    float*  pv1      = (float*)(ws + OFF_PV1);
    float*  pv2      = (float*)(ws + OFF_PV2);
    int*    pi1      = (int*)(ws + OFF_PI1);
    int*    pi2      = (int*)(ws + OFF_PI2);
    int*    amax     = (int*)(ws + OFF_AMAX);
    double* invn64   = (double*)(ws + OFF_INVN64);

    k_norm_atoms<<<AA / 4, 256, 0, stream>>>(atoms, atoms_n, invn64);
    k_prep<<<RTILES + ATILES, 256, 0, stream>>>(emb, atoms_n, embA_hi, embA_lo, atomB_hi, atomB_lo);
    k_score<<<(RTILES / 8) * NSPLIT, 256, 0, stream>>>((const bf16x8*)embA_hi, (const bf16x8*)embA_lo,
                                                       (const bf16x8*)atomB_hi, (const bf16x8*)atomB_lo,
                                                       pv1, pv2, pi1, pi2);
    k_merge<<<NROWS / 256, 256, 0, stream>>>(pv1, pv2, pi1, pi2, emb, atoms, invn64, amax);
    k_epilogue<<<BB, 256, 0, stream>>>(atoms_n, amax, W, b_att, out);
}

// Round 4
// 318.119 us; speedup vs baseline: 3.4707x; 1.1040x over previous
//
#include <hip/hip_runtime.h>
#include <math.h>

#define BB 1024
#define LL 34
#define DD 128
#define AA 4096
#define NROWS (BB * LL)        // 34816
#define RTILES (NROWS / 16)    // 2176 row tiles
#define ATILES (AA / 16)       // 256 atom tiles
#define NSPLIT 4
#define TAU 1e-3f

typedef short bf16x8 __attribute__((ext_vector_type(8)));
typedef float f32x4  __attribute__((ext_vector_type(4)));

// ---- ws layout (bytes) ----
#define OFF_ATOMSN   0u
#define OFF_EMBA_HI  (2097152u)
#define OFF_EMBA_LO  (OFF_EMBA_HI + 8912896u)
#define OFF_ATOMB_HI (OFF_EMBA_LO + 8912896u)
#define OFF_ATOMB_LO (OFF_ATOMB_HI + 1048576u)
#define OFF_PV1      (OFF_ATOMB_LO + 1048576u)
#define OFF_PV2      (OFF_PV1 + 557056u)
#define OFF_PI1      (OFF_PV2 + 557056u)
#define OFF_PI2      (OFF_PI1 + 557056u)
#define OFF_AMAX     (OFF_PI2 + 557056u)
#define OFF_INVN64   (OFF_AMAX + 139264u)

__device__ __forceinline__ unsigned bf16_rne_bits(float x) {
    unsigned u = __float_as_uint(x);
    unsigned r = (u + 0x7FFFu + ((u >> 16) & 1u)) & 0xFFFF0000u;
    return r;
}

// ---------------------------------------------------------------- k_norm_atoms
__global__ __launch_bounds__(256) void k_norm_atoms(const float* __restrict__ atoms,
                                                    float* __restrict__ atoms_n,
                                                    double* __restrict__ invn64) {
    int wid  = threadIdx.x >> 6;
    int lane = threadIdx.x & 63;
    int a = blockIdx.x * 4 + wid;
    float2 v = ((const float2*)(atoms + a * DD))[lane];
    double s = (double)v.x * v.x + (double)v.y * v.y;
    #pragma unroll
    for (int off = 32; off; off >>= 1) s += __shfl_xor(s, off);
    double n = sqrt(s);
    if (n < 1e-12) n = 1e-12;
    double inv = 1.0 / n;
    float invf = (float)inv;
    float2 o; o.x = v.x * invf; o.y = v.y * invf;
    ((float2*)(atoms_n + a * DD))[lane] = o;
    if (lane == 0) invn64[a] = inv;
}

// ---------------------------------------------------------------- k_prep
__global__ __launch_bounds__(256) void k_prep(const float* __restrict__ emb,
                                              const float* __restrict__ atoms_n,
                                              uint4* __restrict__ embA_hi,
                                              uint4* __restrict__ embA_lo,
                                              uint4* __restrict__ atomB_hi,
                                              uint4* __restrict__ atomB_lo) {
    int bid = blockIdx.x;
    const float* src;
    uint4 *dh, *dl;
    int tile;
    if (bid < RTILES) { tile = bid; src = emb; dh = embA_hi; dl = embA_lo; }
    else { tile = bid - RTILES; src = atoms_n; dh = atomB_hi; dl = atomB_lo; }

    int ks = threadIdx.x >> 6, l = threadIdx.x & 63;
    int m = l & 15, koff = ((l >> 4) << 3) + (ks << 5);
    const float* p = src + (size_t)(tile * 16 + m) * DD + koff;
    float4 f0 = ((const float4*)p)[0];
    float4 f1 = ((const float4*)p)[1];
    float xs[8] = {f0.x, f0.y, f0.z, f0.w, f1.x, f1.y, f1.z, f1.w};
    unsigned h[8], lo[8];
    #pragma unroll
    for (int j = 0; j < 8; j++) {
        unsigned hb = bf16_rne_bits(xs[j]);
        h[j] = hb >> 16;
        float res = xs[j] - __uint_as_float(hb);
        lo[j] = bf16_rne_bits(res) >> 16;
    }
    uint4 ph, pl;
    ph.x = h[0] | (h[1] << 16);  ph.y = h[2] | (h[3] << 16);
    ph.z = h[4] | (h[5] << 16);  ph.w = h[6] | (h[7] << 16);
    pl.x = lo[0] | (lo[1] << 16); pl.y = lo[2] | (lo[3] << 16);
    pl.z = lo[4] | (lo[5] << 16); pl.w = lo[6] | (lo[7] << 16);
    size_t idx = (size_t)(tile * 4 + ks) * 64 + l;
    dh[idx] = ph;
    dl[idx] = pl;
}

// ---------------------------------------------------------------- k_score
// split-bf16 MFMA scoring, 6 independent acc chains, prefetched B frags.
// block = 128 threads (2 waves), each wave owns 2 row-tiles; 4 atom-splits.
__global__ __launch_bounds__(128, 2) void k_score(const bf16x8* __restrict__ embA_hi,
                                                  const bf16x8* __restrict__ embA_lo,
                                                  const bf16x8* __restrict__ atomB_hi,
                                                  const bf16x8* __restrict__ atomB_lo,
                                                  float* __restrict__ pv1,
                                                  float* __restrict__ pv2,
                                                  int* __restrict__ pi1,
                                                  int* __restrict__ pi2) {
    const int tid = threadIdx.x;
    const int w = tid >> 6, l = tid & 63;
    const int rb = blockIdx.x >> 2, sp = blockIdx.x & 3;
    const int rt0 = rb * 4 + w * 2;

    bf16x8 a_hi[2][4], a_lo[2][4];
    #pragma unroll
    for (int f = 0; f < 2; f++)
        #pragma unroll
        for (int ks = 0; ks < 4; ks++) {
            size_t idx = (size_t)((rt0 + f) * 4 + ks) * 64 + l;
            a_hi[f][ks] = embA_hi[idx];
            a_lo[f][ks] = embA_lo[idx];
        }

    float v1[8], v2[8];
    int i1[8], i2[8];
    #pragma unroll
    for (int s = 0; s < 8; s++) { v1[s] = -3e38f; v2[s] = -3e38f; i1[s] = 0; i2[s] = 0; }

    const int t0 = sp * (ATILES / NSPLIT);
    const int t1 = t0 + ATILES / NSPLIT;

    bf16x8 bhA[4], blA[4], bhB[4], blB[4];

    #define LOADB(T, BH, BL)                                         \
        {                                                            \
            size_t _b = (size_t)(T) * 256 + l;                       \
            _Pragma("unroll")                                        \
            for (int ks = 0; ks < 4; ks++) {                         \
                BH[ks] = atomB_hi[_b + ks * 64];                     \
                BL[ks] = atomB_lo[_b + ks * 64];                     \
            }                                                        \
        }

    #define PROC(T, BH, BL)                                          \
        {                                                            \
            f32x4 hh0 = {0.f,0.f,0.f,0.f}, hl0 = {0.f,0.f,0.f,0.f}; \
            f32x4 lh0 = {0.f,0.f,0.f,0.f}, hh1 = {0.f,0.f,0.f,0.f}; \
            f32x4 hl1 = {0.f,0.f,0.f,0.f}, lh1 = {0.f,0.f,0.f,0.f}; \
            _Pragma("unroll")                                        \
            for (int ks = 0; ks < 4; ks++) {                         \
                hh0 = __builtin_amdgcn_mfma_f32_16x16x32_bf16(a_hi[0][ks], BH[ks], hh0, 0, 0, 0); \
                hl0 = __builtin_amdgcn_mfma_f32_16x16x32_bf16(a_hi[0][ks], BL[ks], hl0, 0, 0, 0); \
                lh0 = __builtin_amdgcn_mfma_f32_16x16x32_bf16(a_lo[0][ks], BH[ks], lh0, 0, 0, 0); \
                hh1 = __builtin_amdgcn_mfma_f32_16x16x32_bf16(a_hi[1][ks], BH[ks], hh1, 0, 0, 0); \
                hl1 = __builtin_amdgcn_mfma_f32_16x16x32_bf16(a_hi[1][ks], BL[ks], hl1, 0, 0, 0); \
                lh1 = __builtin_amdgcn_mfma_f32_16x16x32_bf16(a_lo[1][ks], BH[ks], lh1, 0, 0, 0); \
            }                                                        \
            f32x4 acc0 = (hh0 + hl0) + lh0;                          \
            f32x4 acc1 = (hh1 + hl1) + lh1;                          \
            const int aidx = (T) * 16 + (l & 15);                    \
            _Pragma("unroll")                                        \
            for (int r = 0; r < 4; r++) {                            \
                float x = acc0[r];                                   \
                bool gt1 = x > v1[r];                                \
                bool gt2 = x > v2[r];                                \
                i2[r] = gt1 ? i1[r] : (gt2 ? aidx : i2[r]);          \
                v2[r] = gt1 ? v1[r] : (gt2 ? x : v2[r]);             \
                i1[r] = gt1 ? aidx : i1[r];                          \
                v1[r] = gt1 ? x : v1[r];                             \
                int s = 4 + r;                                       \
                float y = acc1[r];                                   \
                bool ht1 = y > v1[s];                                \
                bool ht2 = y > v2[s];                                \
                i2[s] = ht1 ? i1[s] : (ht2 ? aidx : i2[s]);          \
                v2[s] = ht1 ? v1[s] : (ht2 ? y : v2[s]);             \
                i1[s] = ht1 ? aidx : i1[s];                          \
                v1[s] = ht1 ? y : v1[s];                             \
            }                                                        \
        }

    LOADB(t0, bhA, blA);
    for (int t = t0; t < t1; t += 2) {
        LOADB(t + 1, bhB, blB);
        PROC(t, bhA, blA);
        if (t + 2 < t1) LOADB(t + 2, bhA, blA);
        PROC(t + 1, bhB, blB);
    }
    #undef LOADB
    #undef PROC

    // butterfly across the 16 lanes of each quad-group (disjoint atom sets)
    #pragma unroll
    for (int m = 1; m <= 8; m <<= 1) {
        #pragma unroll
        for (int s = 0; s < 8; s++) {
            float ov1 = __shfl_xor(v1[s], m);
            float ov2 = __shfl_xor(v2[s], m);
            int   oi1 = __shfl_xor(i1[s], m);
            int   oi2 = __shfl_xor(i2[s], m);
            bool sel = ov1 > v1[s];
            float lv  = sel ? v1[s] : ov1;
            int   li  = sel ? i1[s] : oi1;
            float wv2 = sel ? ov2 : v2[s];
            int   wi2 = sel ? oi2 : i2[s];
            v1[s] = sel ? ov1 : v1[s];
            i1[s] = sel ? oi1 : i1[s];
            bool s2 = lv > wv2;
            v2[s] = s2 ? lv : wv2;
            i2[s] = s2 ? li : wi2;
        }
    }

    if ((l & 15) == 0) {
        int q = l >> 4;
        #pragma unroll
        for (int f = 0; f < 2; f++)
            #pragma unroll
            for (int r = 0; r < 4; r++) {
                int s = f * 4 + r;
                int row = (rt0 + f) * 16 + q * 4 + r;
                size_t o = (size_t)sp * NROWS + row;
                pv1[o] = v1[s];
                pv2[o] = v2[s];
                pi1[o] = i1[s];
                pi2[o] = i2[s];
            }
    }
}

// ---------------------------------------------------------------- k_merge
__global__ __launch_bounds__(256) void k_merge(const float* __restrict__ pv1,
                                               const float* __restrict__ pv2,
                                               const int* __restrict__ pi1,
                                               const int* __restrict__ pi2,
                                               const float* __restrict__ emb,
                                               const float* __restrict__ atoms,
                                               const double* __restrict__ invn64,
                                               int* __restrict__ amax) {
    int r = blockIdx.x * 256 + threadIdx.x;
    float V1 = -3e38f, V2 = -3e38f;
    int I1 = 0, I2 = 0;
    #pragma unroll
    for (int sp = 0; sp < NSPLIT; sp++) {
        size_t o = (size_t)sp * NROWS + r;
        float a1 = pv1[o], a2 = pv2[o];
        int   j1 = pi1[o], j2 = pi2[o];
        bool sel = a1 > V1;
        float lv  = sel ? V1 : a1;
        int   li  = sel ? I1 : j1;
        float wv2 = sel ? a2 : V2;
        int   wi2 = sel ? j2 : I2;
        V1 = sel ? a1 : V1;
        I1 = sel ? j1 : I1;
        bool s2 = lv > wv2;
        V2 = s2 ? lv : wv2;
        I2 = s2 ? li : wi2;
    }
    int winner = I1;
    if (V1 - V2 < TAU) {
        const float4* e4 = (const float4*)(emb + (size_t)r * DD);
        const float4* a4 = (const float4*)(atoms + (size_t)I1 * DD);
        const float4* b4 = (const float4*)(atoms + (size_t)I2 * DD);
        double d1 = 0.0, d2 = 0.0;
        #pragma unroll 8
        for (int k = 0; k < 32; k++) {
            float4 ev = e4[k], av = a4[k], bv = b4[k];
            d1 += (double)ev.x * av.x + (double)ev.y * av.y +
                  (double)ev.z * av.z + (double)ev.w * av.w;
            d2 += (double)ev.x * bv.x + (double)ev.y * bv.y +
                  (double)ev.z * bv.z + (double)ev.w * bv.w;
        }
        double s1 = d1 * invn64[I1];
        double s2v = d2 * invn64[I2];
        if (s2v > s1 || (s2v == s1 && I2 < I1)) winner = I2;
    }
    amax[r] = winner;
}

// ---------------------------------------------------------------- k_epilogue
__global__ __launch_bounds__(256) void k_epilogue(const float* __restrict__ atoms_n,
                                                  const int* __restrict__ amax,
                                                  const float* __restrict__ W,
                                                  const float* __restrict__ b_att,
                                                  float* __restrict__ out) {
    __shared__ __align__(16) float assoc[LL * DD];
    __shared__ int   idxS[LL];
    __shared__ float attS[LL];
    __shared__ float wsum[4][LL];
    __shared__ float sqw[4];

    const int b = blockIdx.x, tid = threadIdx.x;
    const int wid = tid >> 6, lane = tid & 63;

    if (tid < LL) idxS[tid] = amax[b * LL + tid];
    __syncthreads();

    for (int idx = tid; idx < LL * DD; idx += 256) {
        int l = idx >> 7, d = idx & 127;
        assoc[idx] = atoms_n[(size_t)idxS[l] * DD + d];
    }
    __syncthreads();

    float part[LL];
    #pragma unroll
    for (int j = 0; j < LL; j++) part[j] = 0.0f;
    for (int idx = tid; idx < LL * DD; idx += 256) {
        float v = assoc[idx];
        const float* wr = W + (size_t)idx * LL;
        #pragma unroll
        for (int j = 0; j < LL; j++) part[j] = fmaf(v, wr[j], part[j]);
    }
    #pragma unroll
    for (int off = 32; off; off >>= 1) {
        #pragma unroll
        for (int j = 0; j < LL; j++) part[j] += __shfl_down(part[j], off);
    }
    if (lane == 0) {
        #pragma unroll
        for (int j = 0; j < LL; j++) wsum[wid][j] = part[j];
    }
    __syncthreads();
    if (tid < LL)
        attS[tid] = b_att[tid] + wsum[0][tid] + wsum[1][tid] + wsum[2][tid] + wsum[3][tid];
    __syncthreads();

    float o = 0.0f;
    if (tid < DD) {
        #pragma unroll
        for (int l = 0; l < LL; l++) o = fmaf(attS[l], assoc[l * DD + tid], o);
    }
    float sq = (tid < DD) ? o * o : 0.0f;
    #pragma unroll
    for (int off = 32; off; off >>= 1) sq += __shfl_xor(sq, off);
    if (lane == 0) sqw[wid] = sq;
    __syncthreads();
    float tot = sqw[0] + sqw[1] + sqw[2] + sqw[3];
    float n = sqrtf(tot);
    float inv = 1.0f / fmaxf(n, 1e-12f);
    if (tid < DD) out[(size_t)b * DD + tid] = o * inv;
}

// ---------------------------------------------------------------- launcher
extern "C" void kernel_launch(void* const* d_in, const int* in_sizes, int n_in,
                              void* d_out, int out_size, void* d_ws, size_t ws_size,
                              hipStream_t stream) {
    const float* emb   = (const float*)d_in[0];
    const float* atoms = (const float*)d_in[1];
    const float* W     = (const float*)d_in[2];
    const float* b_att = (const float*)d_in[3];
    float* out = (float*)d_out;

    char* ws = (char*)d_ws;
    float*  atoms_n  = (float*)(ws + OFF_ATOMSN);
    uint4*  embA_hi  = (uint4*)(ws + OFF_EMBA_HI);
    uint4*  embA_lo  = (uint4*)(ws + OFF_EMBA_LO);
    uint4*  atomB_hi = (uint4*)(ws + OFF_ATOMB_HI);
    uint4*  atomB_lo = (uint4*)(ws + OFF_ATOMB_LO);
    float*  pv1      = (float*)(ws + OFF_PV1);
    float*  pv2      = (float*)(ws + OFF_PV2);
    int*    pi1      = (int*)(ws + OFF_PI1);
    int*    pi2      = (int*)(ws + OFF_PI2);
    int*    amax     = (int*)(ws + OFF_AMAX);
    double* invn64   = (double*)(ws + OFF_INVN64);

    k_norm_atoms<<<AA / 4, 256, 0, stream>>>(atoms, atoms_n, invn64);
    k_prep<<<RTILES + ATILES, 256, 0, stream>>>(emb, atoms_n, embA_hi, embA_lo, atomB_hi, atomB_lo);
    k_score<<<(RTILES / 4) * NSPLIT, 128, 0, stream>>>((const bf16x8*)embA_hi, (const bf16x8*)embA_lo,
                                                       (const bf16x8*)atomB_hi, (const bf16x8*)atomB_lo,
                                                       pv1, pv2, pi1, pi2);
    k_merge<<<NROWS / 256, 256, 0, stream>>>(pv1, pv2, pi1, pi2, emb, atoms, invn64, amax);
    k_epilogue<<<BB, 256, 0, stream>>>(atoms_n, amax, W, b_att, out);
}

// Round 5
// 279.768 us; speedup vs baseline: 3.9464x; 1.1371x over previous
//
#include <hip/hip_runtime.h>
#include <math.h>

#define BB 1024
#define LL 34
#define DD 128
#define AA 4096
#define NROWS (BB * LL)        // 34816
#define RTILES (NROWS / 16)    // 2176 row tiles
#define ATILES (AA / 16)       // 256 atom tiles
#define NSPLIT 4
#define TPS (ATILES / NSPLIT)  // 64 tiles per split
#define NCHUNK (TPS / 2)       // 32 chunks of 2 tiles
#define TAU 1e-3f

typedef short bf16x8 __attribute__((ext_vector_type(8)));
typedef float f32x4  __attribute__((ext_vector_type(4)));

// ---- ws layout (bytes) ----
#define OFF_ATOMSN   0u
#define OFF_EMBA_HI  (2097152u)
#define OFF_EMBA_LO  (OFF_EMBA_HI + 8912896u)
#define OFF_ATOMB_HI (OFF_EMBA_LO + 8912896u)
#define OFF_ATOMB_LO (OFF_ATOMB_HI + 1048576u)
#define OFF_PV1      (OFF_ATOMB_LO + 1048576u)
#define OFF_PV2      (OFF_PV1 + 557056u)
#define OFF_PI1      (OFF_PV2 + 557056u)
#define OFF_PI2      (OFF_PI1 + 557056u)
#define OFF_INVN64   (OFF_PI2 + 557056u)

__device__ __forceinline__ unsigned bf16_rne_bits(float x) {
    unsigned u = __float_as_uint(x);
    unsigned r = (u + 0x7FFFu + ((u >> 16) & 1u)) & 0xFFFF0000u;
    return r;
}

// ---------------------------------------------------------------- k_prep
// Fused: (a) normalize atoms (fp64 norms) for atom tiles, (b) swizzle both
// emb and atoms_n into MFMA-fragment-linear hi/lo split-bf16 arrays.
__global__ __launch_bounds__(256) void k_prep(const float* __restrict__ emb,
                                              const float* __restrict__ atoms,
                                              float* __restrict__ atoms_n,
                                              double* __restrict__ invn64,
                                              uint4* __restrict__ embA_hi,
                                              uint4* __restrict__ embA_lo,
                                              uint4* __restrict__ atomB_hi,
                                              uint4* __restrict__ atomB_lo) {
    __shared__ double part[16][17];
    const int bid = blockIdx.x;
    const int ks = threadIdx.x >> 6, l = threadIdx.x & 63;
    const int m = l & 15, koff = ((l >> 4) << 3) + (ks << 5);

    float xs[8];
    int tile;
    uint4 *dh, *dl;

    if (bid < RTILES) {                         // embedding tile: plain swizzle
        tile = bid;
        const float* p = emb + (size_t)(tile * 16 + m) * DD + koff;
        float4 f0 = ((const float4*)p)[0];
        float4 f1 = ((const float4*)p)[1];
        xs[0]=f0.x; xs[1]=f0.y; xs[2]=f0.z; xs[3]=f0.w;
        xs[4]=f1.x; xs[5]=f1.y; xs[6]=f1.z; xs[7]=f1.w;
        dh = embA_hi; dl = embA_lo;
    } else {                                    // atom tile: normalize inline
        tile = bid - RTILES;
        const float* p = atoms + (size_t)(tile * 16 + m) * DD + koff;
        float4 f0 = ((const float4*)p)[0];
        float4 f1 = ((const float4*)p)[1];
        xs[0]=f0.x; xs[1]=f0.y; xs[2]=f0.z; xs[3]=f0.w;
        xs[4]=f1.x; xs[5]=f1.y; xs[6]=f1.z; xs[7]=f1.w;
        double ssq = 0.0;
        #pragma unroll
        for (int j = 0; j < 8; j++) ssq += (double)xs[j] * xs[j];
        part[m][ks * 4 + (l >> 4)] = ssq;
        __syncthreads();
        double tot = 0.0;
        #pragma unroll
        for (int q = 0; q < 16; q++) tot += part[m][q];
        double n = sqrt(tot);
        if (n < 1e-12) n = 1e-12;
        double inv = 1.0 / n;
        float invf = (float)inv;
        #pragma unroll
        for (int j = 0; j < 8; j++) xs[j] *= invf;
        float* q = atoms_n + (size_t)(tile * 16 + m) * DD + koff;
        float4 o0, o1;
        o0.x=xs[0]; o0.y=xs[1]; o0.z=xs[2]; o0.w=xs[3];
        o1.x=xs[4]; o1.y=xs[5]; o1.z=xs[6]; o1.w=xs[7];
        ((float4*)q)[0] = o0; ((float4*)q)[1] = o1;
        if (ks == 0 && (l >> 4) == 0) invn64[tile * 16 + m] = inv;
        dh = atomB_hi; dl = atomB_lo;
    }

    unsigned h[8], lo[8];
    #pragma unroll
    for (int j = 0; j < 8; j++) {
        unsigned hb = bf16_rne_bits(xs[j]);
        h[j] = hb >> 16;
        float res = xs[j] - __uint_as_float(hb);
        lo[j] = bf16_rne_bits(res) >> 16;
    }
    uint4 ph, pl;
    ph.x = h[0] | (h[1] << 16);  ph.y = h[2] | (h[3] << 16);
    ph.z = h[4] | (h[5] << 16);  ph.w = h[6] | (h[7] << 16);
    pl.x = lo[0] | (lo[1] << 16); pl.y = lo[2] | (lo[3] << 16);
    pl.z = lo[4] | (lo[5] << 16); pl.w = lo[6] | (lo[7] << 16);
    size_t idx = (size_t)(tile * 4 + ks) * 64 + l;
    dh[idx] = ph;
    dl[idx] = pl;
}

// ---------------------------------------------------------------- k_score
// split-bf16 MFMA scoring; B fragments LDS-shared across the block's 4 waves,
// staged via global_load_lds (width=16), double-buffered 2-tile chunks.
__global__ __launch_bounds__(256, 3) void k_score(const bf16x8* __restrict__ embA_hi,
                                                  const bf16x8* __restrict__ embA_lo,
                                                  const uint4* __restrict__ atomB_hi,
                                                  const uint4* __restrict__ atomB_lo,
                                                  float* __restrict__ pv1,
                                                  float* __restrict__ pv2,
                                                  int* __restrict__ pi1,
                                                  int* __restrict__ pi2) {
    __shared__ uint4 sbuf[2][1024];            // 2 x 16 KB: [0,8K)=hi, [8K,16K)=lo

    const int tid = threadIdx.x;
    const int w = tid >> 6, l = tid & 63;
    const int rb = blockIdx.x >> 2, sp = blockIdx.x & 3;
    const int rt0 = rb * 8 + w * 2;

    bf16x8 a_hi[2][4], a_lo[2][4];
    #pragma unroll
    for (int f = 0; f < 2; f++)
        #pragma unroll
        for (int ks = 0; ks < 4; ks++) {
            size_t idx = (size_t)((rt0 + f) * 4 + ks) * 64 + l;
            a_hi[f][ks] = embA_hi[idx];
            a_lo[f][ks] = embA_lo[idx];
        }

    float v1[8], v2[8];
    int i1[8], i2[8];
    #pragma unroll
    for (int s = 0; s < 8; s++) { v1[s] = -3e38f; v2[s] = -3e38f; i1[s] = 0; i2[s] = 0; }

    const char* hiB = (const char*)atomB_hi;
    const char* loB = (const char*)atomB_lo;

    #define STAGE(C, BUF)                                                          \
        {                                                                          \
            size_t _tb = (size_t)(sp * TPS + (C) * 2) * 4096;                      \
            _Pragma("unroll")                                                      \
            for (int r = 0; r < 4; r++) {                                          \
                const char* _src = (r < 2) ? (hiB + _tb + r * 4096)                \
                                           : (loB + _tb + (r - 2) * 4096);         \
                uint32_t* _dst = (uint32_t*)((char*)&sbuf[BUF][0] + r * 4096 + w * 1024); \
                __builtin_amdgcn_global_load_lds((const uint32_t*)(_src + tid * 16), \
                                                 _dst, 16, 0, 0);                  \
            }                                                                      \
        }

    STAGE(0, 0);
    __syncthreads();

    for (int c = 0; c < NCHUNK; c++) {
        const int buf = c & 1;
        if (c + 1 < NCHUNK) STAGE(c + 1, buf ^ 1);

        #pragma unroll
        for (int tt = 0; tt < 2; tt++) {
            bf16x8 bh[4], bl[4];
            #pragma unroll
            for (int ks = 0; ks < 4; ks++) {
                bh[ks] = *(const bf16x8*)((const char*)&sbuf[buf][0] + tt * 4096 + ks * 1024 + l * 16);
                bl[ks] = *(const bf16x8*)((const char*)&sbuf[buf][0] + 8192 + tt * 4096 + ks * 1024 + l * 16);
            }
            f32x4 hh0 = {0.f,0.f,0.f,0.f}, hl0 = {0.f,0.f,0.f,0.f}, lh0 = {0.f,0.f,0.f,0.f};
            f32x4 hh1 = {0.f,0.f,0.f,0.f}, hl1 = {0.f,0.f,0.f,0.f}, lh1 = {0.f,0.f,0.f,0.f};
            #pragma unroll
            for (int ks = 0; ks < 4; ks++) {
                hh0 = __builtin_amdgcn_mfma_f32_16x16x32_bf16(a_hi[0][ks], bh[ks], hh0, 0, 0, 0);
                hl0 = __builtin_amdgcn_mfma_f32_16x16x32_bf16(a_hi[0][ks], bl[ks], hl0, 0, 0, 0);
                lh0 = __builtin_amdgcn_mfma_f32_16x16x32_bf16(a_lo[0][ks], bh[ks], lh0, 0, 0, 0);
                hh1 = __builtin_amdgcn_mfma_f32_16x16x32_bf16(a_hi[1][ks], bh[ks], hh1, 0, 0, 0);
                hl1 = __builtin_amdgcn_mfma_f32_16x16x32_bf16(a_hi[1][ks], bl[ks], hl1, 0, 0, 0);
                lh1 = __builtin_amdgcn_mfma_f32_16x16x32_bf16(a_lo[1][ks], bh[ks], lh1, 0, 0, 0);
            }
            f32x4 acc0 = (hh0 + hl0) + lh0;
            f32x4 acc1 = (hh1 + hl1) + lh1;
            const int aidx = (sp * TPS + c * 2 + tt) * 16 + (l & 15);
            #pragma unroll
            for (int r = 0; r < 4; r++) {
                float x = acc0[r];
                bool gt1 = x > v1[r];
                bool gt2 = x > v2[r];
                i2[r] = gt1 ? i1[r] : (gt2 ? aidx : i2[r]);
                v2[r] = gt1 ? v1[r] : (gt2 ? x : v2[r]);
                i1[r] = gt1 ? aidx : i1[r];
                v1[r] = gt1 ? x : v1[r];
                int s = 4 + r;
                float y = acc1[r];
                bool ht1 = y > v1[s];
                bool ht2 = y > v2[s];
                i2[s] = ht1 ? i1[s] : (ht2 ? aidx : i2[s]);
                v2[s] = ht1 ? v1[s] : (ht2 ? y : v2[s]);
                i1[s] = ht1 ? aidx : i1[s];
                v1[s] = ht1 ? y : v1[s];
            }
        }
        __syncthreads();   // all waves done reading sbuf[buf]; drains next stage
    }
    #undef STAGE

    // butterfly across the 16 lanes of each quad-group (disjoint atom sets)
    #pragma unroll
    for (int m = 1; m <= 8; m <<= 1) {
        #pragma unroll
        for (int s = 0; s < 8; s++) {
            float ov1 = __shfl_xor(v1[s], m);
            float ov2 = __shfl_xor(v2[s], m);
            int   oi1 = __shfl_xor(i1[s], m);
            int   oi2 = __shfl_xor(i2[s], m);
            bool sel = ov1 > v1[s];
            float lv  = sel ? v1[s] : ov1;
            int   li  = sel ? i1[s] : oi1;
            float wv2 = sel ? ov2 : v2[s];
            int   wi2 = sel ? oi2 : i2[s];
            v1[s] = sel ? ov1 : v1[s];
            i1[s] = sel ? oi1 : i1[s];
            bool s2 = lv > wv2;
            v2[s] = s2 ? lv : wv2;
            i2[s] = s2 ? li : wi2;
        }
    }

    if ((l & 15) == 0) {
        int q = l >> 4;
        #pragma unroll
        for (int f = 0; f < 2; f++)
            #pragma unroll
            for (int r = 0; r < 4; r++) {
                int s = f * 4 + r;
                int row = (rt0 + f) * 16 + q * 4 + r;
                size_t o = (size_t)sp * NROWS + row;
                pv1[o] = v1[s];
                pv2[o] = v2[s];
                pi1[o] = i1[s];
                pi2[o] = i2[s];
            }
    }
}

// ---------------------------------------------------------------- k_epilogue
// Fused: merge 4-split top-2, wave-parallel fp64 rescore of near-ties,
// gather assoc, att = assoc_flat @ W + b, out = normalize(att @ assoc).
__global__ __launch_bounds__(256) void k_epilogue(const float* __restrict__ atoms_n,
                                                  const float* __restrict__ pv1,
                                                  const float* __restrict__ pv2,
                                                  const int* __restrict__ pi1,
                                                  const int* __restrict__ pi2,
                                                  const float* __restrict__ emb,
                                                  const float* __restrict__ atoms,
                                                  const double* __restrict__ invn64,
                                                  const float* __restrict__ W,
                                                  const float* __restrict__ b_att,
                                                  float* __restrict__ out) {
    __shared__ __align__(16) float assoc[LL * DD];
    __shared__ int   amaxS[LL];
    __shared__ float attS[LL];
    __shared__ float wsum[4][LL];
    __shared__ float sqw[4];
    __shared__ int   flagCnt;
    __shared__ int   flagRow[LL], flagA[LL], flagB[LL];

    const int b = blockIdx.x, tid = threadIdx.x;
    const int wid = tid >> 6, lane = tid & 63;

    if (tid == 0) flagCnt = 0;
    __syncthreads();

    if (tid < LL) {
        int r = b * LL + tid;
        float V1 = -3e38f, V2 = -3e38f;
        int I1 = 0, I2 = 0;
        #pragma unroll
        for (int sp = 0; sp < NSPLIT; sp++) {
            size_t o = (size_t)sp * NROWS + r;
            float a1 = pv1[o], a2 = pv2[o];
            int   j1 = pi1[o], j2 = pi2[o];
            bool sel = a1 > V1;
            float lv  = sel ? V1 : a1;
            int   li  = sel ? I1 : j1;
            float wv2 = sel ? a2 : V2;
            int   wi2 = sel ? j2 : I2;
            V1 = sel ? a1 : V1;
            I1 = sel ? j1 : I1;
            bool s2 = lv > wv2;
            V2 = s2 ? lv : wv2;
            I2 = s2 ? li : wi2;
        }
        amaxS[tid] = I1;
        if (V1 - V2 < TAU) {
            int k = atomicAdd(&flagCnt, 1);
            flagRow[k] = tid; flagA[k] = I1; flagB[k] = I2;
        }
    }
    __syncthreads();

    const int cnt = flagCnt;
    for (int fi = wid; fi < cnt; fi += 4) {
        int row = flagRow[fi], I1 = flagA[fi], I2 = flagB[fi];
        const float* e = emb + (size_t)(b * LL + row) * DD + 2 * lane;
        const float* a = atoms + (size_t)I1 * DD + 2 * lane;
        const float* c = atoms + (size_t)I2 * DD + 2 * lane;
        double p1 = (double)e[0] * a[0] + (double)e[1] * a[1];
        double p2 = (double)e[0] * c[0] + (double)e[1] * c[1];
        #pragma unroll
        for (int m = 1; m <= 32; m <<= 1) {
            p1 += __shfl_xor(p1, m);
            p2 += __shfl_xor(p2, m);
        }
        if (lane == 0) {
            double s1 = p1 * invn64[I1];
            double s2 = p2 * invn64[I2];
            if (s2 > s1 || (s2 == s1 && I2 < I1)) amaxS[row] = I2;
        }
    }
    __syncthreads();

    for (int idx = tid; idx < LL * DD; idx += 256) {
        int l = idx >> 7, d = idx & 127;
        assoc[idx] = atoms_n[(size_t)amaxS[l] * DD + d];
    }
    __syncthreads();

    float part[LL];
    #pragma unroll
    for (int j = 0; j < LL; j++) part[j] = 0.0f;
    for (int idx = tid; idx < LL * DD; idx += 256) {
        float v = assoc[idx];
        const float* wr = W + (size_t)idx * LL;
        #pragma unroll
        for (int j = 0; j < LL; j++) part[j] = fmaf(v, wr[j], part[j]);
    }
    #pragma unroll
    for (int off = 32; off; off >>= 1) {
        #pragma unroll
        for (int j = 0; j < LL; j++) part[j] += __shfl_down(part[j], off);
    }
    if (lane == 0) {
        #pragma unroll
        for (int j = 0; j < LL; j++) wsum[wid][j] = part[j];
    }
    __syncthreads();
    if (tid < LL)
        attS[tid] = b_att[tid] + wsum[0][tid] + wsum[1][tid] + wsum[2][tid] + wsum[3][tid];
    __syncthreads();

    float o = 0.0f;
    if (tid < DD) {
        #pragma unroll
        for (int l = 0; l < LL; l++) o = fmaf(attS[l], assoc[l * DD + tid], o);
    }
    float sq = (tid < DD) ? o * o : 0.0f;
    #pragma unroll
    for (int off = 32; off; off >>= 1) sq += __shfl_xor(sq, off);
    if (lane == 0) sqw[wid] = sq;
    __syncthreads();
    float tot = sqw[0] + sqw[1] + sqw[2] + sqw[3];
    float n = sqrtf(tot);
    float inv = 1.0f / fmaxf(n, 1e-12f);
    if (tid < DD) out[(size_t)b * DD + tid] = o * inv;
}

// ---------------------------------------------------------------- launcher
extern "C" void kernel_launch(void* const* d_in, const int* in_sizes, int n_in,
                              void* d_out, int out_size, void* d_ws, size_t ws_size,
                              hipStream_t stream) {
    const float* emb   = (const float*)d_in[0];
    const float* atoms = (const float*)d_in[1];
    const float* W     = (const float*)d_in[2];
    const float* b_att = (const float*)d_in[3];
    float* out = (float*)d_out;

    char* ws = (char*)d_ws;
    float*  atoms_n  = (float*)(ws + OFF_ATOMSN);
    uint4*  embA_hi  = (uint4*)(ws + OFF_EMBA_HI);
    uint4*  embA_lo  = (uint4*)(ws + OFF_EMBA_LO);
    uint4*  atomB_hi = (uint4*)(ws + OFF_ATOMB_HI);
    uint4*  atomB_lo = (uint4*)(ws + OFF_ATOMB_LO);
    float*  pv1      = (float*)(ws + OFF_PV1);
    float*  pv2      = (float*)(ws + OFF_PV2);
    int*    pi1      = (int*)(ws + OFF_PI1);
    int*    pi2      = (int*)(ws + OFF_PI2);
    double* invn64   = (double*)(ws + OFF_INVN64);

    k_prep<<<RTILES + ATILES, 256, 0, stream>>>(emb, atoms, atoms_n, invn64,
                                                embA_hi, embA_lo, atomB_hi, atomB_lo);
    k_score<<<(RTILES / 8) * NSPLIT, 256, 0, stream>>>((const bf16x8*)embA_hi, (const bf16x8*)embA_lo,
                                                       atomB_hi, atomB_lo,
                                                       pv1, pv2, pi1, pi2);
    k_epilogue<<<BB, 256, 0, stream>>>(atoms_n, pv1, pv2, pi1, pi2,
                                       emb, atoms, invn64, W, b_att, out);
}

// Round 6
// 269.038 us; speedup vs baseline: 4.1038x; 1.0399x over previous
//
#include <hip/hip_runtime.h>
#include <math.h>

#define BB 1024
#define LL 34
#define DD 128
#define AA 4096
#define NROWS (BB * LL)        // 34816
#define RTILES (NROWS / 16)    // 2176 row tiles
#define ATILES (AA / 16)       // 256 atom tiles
#define NSPLIT 8
#define TPS (ATILES / NSPLIT)  // 32 tiles per split
#define NCHUNK (TPS / 2)       // 16 chunks of 2 tiles
#define TAU 1e-3f

typedef short bf16x8 __attribute__((ext_vector_type(8)));
typedef float f32x4  __attribute__((ext_vector_type(4)));

// ---- ws layout (bytes), total ~24.43 MB ----
#define OFF_EMBA_HI  0u
#define OFF_EMBA_LO  8912896u
#define OFF_ATOMB_HI 17825792u
#define OFF_ATOMB_LO 18874368u
#define OFF_PV1      19922944u
#define OFF_PV2      (OFF_PV1 + 1114112u)
#define OFF_PI1      (OFF_PV2 + 1114112u)
#define OFF_PI2      (OFF_PI1 + 1114112u)
#define OFF_INVN64   (OFF_PI2 + 1114112u)
#define OFF_INVNF    (OFF_INVN64 + 32768u)

__device__ __forceinline__ unsigned bf16_rne_bits(float x) {
    unsigned u = __float_as_uint(x);
    return (u + 0x7FFFu + ((u >> 16) & 1u)) & 0xFFFF0000u;
}

// ---------------------------------------------------------------- k_prep
// Fused: normalize atoms (fp64 norms) + swizzle emb / atoms_n into
// MFMA-fragment-linear hi/lo split-bf16 arrays. atoms_n is NOT materialized;
// epilogue rescales raw atoms by invnF.
__global__ __launch_bounds__(256) void k_prep(const float* __restrict__ emb,
                                              const float* __restrict__ atoms,
                                              double* __restrict__ invn64,
                                              float* __restrict__ invnF,
                                              uint4* __restrict__ embA_hi,
                                              uint4* __restrict__ embA_lo,
                                              uint4* __restrict__ atomB_hi,
                                              uint4* __restrict__ atomB_lo) {
    __shared__ double part[16][17];
    const int bid = blockIdx.x;
    const int ks = threadIdx.x >> 6, l = threadIdx.x & 63;
    const int m = l & 15, koff = ((l >> 4) << 3) + (ks << 5);

    float xs[8];
    int tile;
    uint4 *dh, *dl;

    if (bid < RTILES) {                         // embedding tile: plain swizzle
        tile = bid;
        const float* p = emb + (size_t)(tile * 16 + m) * DD + koff;
        float4 f0 = ((const float4*)p)[0];
        float4 f1 = ((const float4*)p)[1];
        xs[0]=f0.x; xs[1]=f0.y; xs[2]=f0.z; xs[3]=f0.w;
        xs[4]=f1.x; xs[5]=f1.y; xs[6]=f1.z; xs[7]=f1.w;
        dh = embA_hi; dl = embA_lo;
    } else {                                    // atom tile: normalize inline
        tile = bid - RTILES;
        const float* p = atoms + (size_t)(tile * 16 + m) * DD + koff;
        float4 f0 = ((const float4*)p)[0];
        float4 f1 = ((const float4*)p)[1];
        xs[0]=f0.x; xs[1]=f0.y; xs[2]=f0.z; xs[3]=f0.w;
        xs[4]=f1.x; xs[5]=f1.y; xs[6]=f1.z; xs[7]=f1.w;
        double ssq = 0.0;
        #pragma unroll
        for (int j = 0; j < 8; j++) ssq += (double)xs[j] * xs[j];
        part[m][ks * 4 + (l >> 4)] = ssq;
        __syncthreads();
        double tot = 0.0;
        #pragma unroll
        for (int q = 0; q < 16; q++) tot += part[m][q];
        double n = sqrt(tot);
        if (n < 1e-12) n = 1e-12;
        double inv = 1.0 / n;
        float invf = (float)inv;
        #pragma unroll
        for (int j = 0; j < 8; j++) xs[j] *= invf;
        if (ks == 0 && (l >> 4) == 0) {
            invn64[tile * 16 + m] = inv;
            invnF[tile * 16 + m] = invf;
        }
        dh = atomB_hi; dl = atomB_lo;
    }

    unsigned h[8], lo[8];
    #pragma unroll
    for (int j = 0; j < 8; j++) {
        unsigned hb = bf16_rne_bits(xs[j]);
        h[j] = hb >> 16;
        float res = xs[j] - __uint_as_float(hb);
        lo[j] = bf16_rne_bits(res) >> 16;
    }
    uint4 ph, pl;
    ph.x = h[0] | (h[1] << 16);  ph.y = h[2] | (h[3] << 16);
    ph.z = h[4] | (h[5] << 16);  ph.w = h[6] | (h[7] << 16);
    pl.x = lo[0] | (lo[1] << 16); pl.y = lo[2] | (lo[3] << 16);
    pl.z = lo[4] | (lo[5] << 16); pl.w = lo[6] | (lo[7] << 16);
    size_t idx = (size_t)(tile * 4 + ks) * 64 + l;
    dh[idx] = ph;
    dl[idx] = pl;
}

// ---------------------------------------------------------------- k_score
// split-bf16 MFMA scoring. R=4 row-tiles per wave (64 rows). B LDS-shared
// across 4 waves via global_load_lds (16B), double-buffered 2-tile chunks.
// In-loop top-2 via packed keys: low 5 mantissa bits carry the local tile id
// (perturbation <= 31 ulp ~ 7e-6, folded into the TAU rescore margin).
__global__ __launch_bounds__(256, 2) void k_score(const bf16x8* __restrict__ embA_hi,
                                                  const bf16x8* __restrict__ embA_lo,
                                                  const uint4* __restrict__ atomB_hi,
                                                  const uint4* __restrict__ atomB_lo,
                                                  float* __restrict__ pv1,
                                                  float* __restrict__ pv2,
                                                  int* __restrict__ pi1,
                                                  int* __restrict__ pi2) {
    __shared__ uint4 sbuf[2][1024];            // 2 x 16 KB

    const int tid = threadIdx.x;
    const int w = tid >> 6, l = tid & 63;
    const int rb = blockIdx.x >> 3, sp = blockIdx.x & 7;
    const int rt0 = rb * 16 + w * 4;

    bf16x8 a_hi[4][4], a_lo[4][4];
    #pragma unroll
    for (int f = 0; f < 4; f++)
        #pragma unroll
        for (int ks = 0; ks < 4; ks++) {
            size_t idx = (size_t)((rt0 + f) * 4 + ks) * 64 + l;
            a_hi[f][ks] = embA_hi[idx];
            a_lo[f][ks] = embA_lo[idx];
        }

    float v1[16], v2[16];
    #pragma unroll
    for (int s = 0; s < 16; s++) { v1[s] = -3e38f; v2[s] = -3e38f; }

    const char* hiB = (const char*)atomB_hi;
    const char* loB = (const char*)atomB_lo;

    #define STAGE(C, BUF)                                                          \
        {                                                                          \
            size_t _tb = (size_t)(sp * TPS + (C) * 2) * 4096;                      \
            _Pragma("unroll")                                                      \
            for (int r = 0; r < 4; r++) {                                          \
                const char* _src = (r < 2) ? (hiB + _tb + r * 4096)                \
                                           : (loB + _tb + (r - 2) * 4096);         \
                uint32_t* _dst = (uint32_t*)((char*)&sbuf[BUF][0] + r * 4096 + w * 1024); \
                __builtin_amdgcn_global_load_lds((const uint32_t*)(_src + tid * 16), \
                                                 _dst, 16, 0, 0);                  \
            }                                                                      \
        }

    STAGE(0, 0);
    __syncthreads();

    for (int c = 0; c < NCHUNK; c++) {
        const int buf = c & 1;
        if (c + 1 < NCHUNK) STAGE(c + 1, buf ^ 1);

        #pragma unroll
        for (int tt = 0; tt < 2; tt++) {
            bf16x8 bh[4], bl[4];
            #pragma unroll
            for (int ks = 0; ks < 4; ks++) {
                bh[ks] = *(const bf16x8*)((const char*)&sbuf[buf][0] + tt * 4096 + ks * 1024 + l * 16);
                bl[ks] = *(const bf16x8*)((const char*)&sbuf[buf][0] + 8192 + tt * 4096 + ks * 1024 + l * 16);
            }
            f32x4 hh[4], mx[4];
            #pragma unroll
            for (int f = 0; f < 4; f++) { hh[f] = (f32x4){0.f,0.f,0.f,0.f}; mx[f] = (f32x4){0.f,0.f,0.f,0.f}; }
            #pragma unroll
            for (int ks = 0; ks < 4; ks++) {
                #pragma unroll
                for (int f = 0; f < 4; f++) {
                    hh[f] = __builtin_amdgcn_mfma_f32_16x16x32_bf16(a_hi[f][ks], bh[ks], hh[f], 0, 0, 0);
                    mx[f] = __builtin_amdgcn_mfma_f32_16x16x32_bf16(a_hi[f][ks], bl[ks], mx[f], 0, 0, 0);
                }
            }
            #pragma unroll
            for (int ks = 0; ks < 4; ks++) {
                #pragma unroll
                for (int f = 0; f < 4; f++)
                    mx[f] = __builtin_amdgcn_mfma_f32_16x16x32_bf16(a_lo[f][ks], bh[ks], mx[f], 0, 0, 0);
            }
            const unsigned tl = (unsigned)(c * 2 + tt);   // 0..31
            #pragma unroll
            for (int f = 0; f < 4; f++) {
                f32x4 acc = hh[f] + mx[f];
                #pragma unroll
                for (int r = 0; r < 4; r++) {
                    int s = f * 4 + r;
                    float xq = __uint_as_float((__float_as_uint(acc[r]) & 0xFFFFFFE0u) | tl);
                    float m_ = fminf(xq, v1[s]);
                    v1[s] = fmaxf(v1[s], xq);
                    v2[s] = fmaxf(v2[s], m_);
                }
            }
        }
        __syncthreads();
    }
    #undef STAGE

    // unpack keys -> (value, global atom index)
    float vv1[16], vv2[16];
    int jj1[16], jj2[16];
    const int col = l & 15;
    #pragma unroll
    for (int s = 0; s < 16; s++) {
        unsigned u1 = __float_as_uint(v1[s]);
        unsigned u2 = __float_as_uint(v2[s]);
        vv1[s] = __uint_as_float(u1 & 0xFFFFFFE0u);
        vv2[s] = __uint_as_float(u2 & 0xFFFFFFE0u);
        jj1[s] = (sp * TPS + (int)(u1 & 31u)) * 16 + col;
        jj2[s] = (sp * TPS + (int)(u2 & 31u)) * 16 + col;
    }

    // butterfly across the 16 lanes of each quad-group (disjoint atom sets)
    #pragma unroll
    for (int m = 1; m <= 8; m <<= 1) {
        #pragma unroll
        for (int s = 0; s < 16; s++) {
            float ov1 = __shfl_xor(vv1[s], m);
            float ov2 = __shfl_xor(vv2[s], m);
            int   oi1 = __shfl_xor(jj1[s], m);
            int   oi2 = __shfl_xor(jj2[s], m);
            bool sel = ov1 > vv1[s];
            float lv  = sel ? vv1[s] : ov1;
            int   li  = sel ? jj1[s] : oi1;
            float wv2 = sel ? ov2 : vv2[s];
            int   wi2 = sel ? oi2 : jj2[s];
            vv1[s] = sel ? ov1 : vv1[s];
            jj1[s] = sel ? oi1 : jj1[s];
            bool s2 = lv > wv2;
            vv2[s] = s2 ? lv : wv2;
            jj2[s] = s2 ? li : wi2;
        }
    }

    if ((l & 15) == 0) {
        int q = l >> 4;
        #pragma unroll
        for (int f = 0; f < 4; f++)
            #pragma unroll
            for (int r = 0; r < 4; r++) {
                int s = f * 4 + r;
                int row = (rt0 + f) * 16 + q * 4 + r;
                size_t o = (size_t)sp * NROWS + row;
                pv1[o] = vv1[s];
                pv2[o] = vv2[s];
                pi1[o] = jj1[s];
                pi2[o] = jj2[s];
            }
    }
}

// ---------------------------------------------------------------- k_epilogue
// Fused: merge 8-split top-2, wave-parallel fp64 rescore of near-ties,
// gather assoc (= atoms * invnF), att = assoc_flat @ W + b,
// out = normalize(att @ assoc).
__global__ __launch_bounds__(256) void k_epilogue(const float* __restrict__ pv1,
                                                  const float* __restrict__ pv2,
                                                  const int* __restrict__ pi1,
                                                  const int* __restrict__ pi2,
                                                  const float* __restrict__ emb,
                                                  const float* __restrict__ atoms,
                                                  const double* __restrict__ invn64,
                                                  const float* __restrict__ invnF,
                                                  const float* __restrict__ W,
                                                  const float* __restrict__ b_att,
                                                  float* __restrict__ out) {
    __shared__ __align__(16) float assoc[LL * DD];
    __shared__ int   amaxS[LL];
    __shared__ float invS[LL];
    __shared__ float attS[LL];
    __shared__ float wsum[4][LL];
    __shared__ float sqw[4];
    __shared__ int   flagCnt;
    __shared__ int   flagRow[LL], flagA[LL], flagB[LL];

    const int b = blockIdx.x, tid = threadIdx.x;
    const int wid = tid >> 6, lane = tid & 63;

    if (tid == 0) flagCnt = 0;
    __syncthreads();

    if (tid < LL) {
        int r = b * LL + tid;
        float V1 = -3e38f, V2 = -3e38f;
        int I1 = 0, I2 = 0;
        #pragma unroll
        for (int sp = 0; sp < NSPLIT; sp++) {
            size_t o = (size_t)sp * NROWS + r;
            float a1 = pv1[o], a2 = pv2[o];
            int   j1 = pi1[o], j2 = pi2[o];
            bool sel = a1 > V1;
            float lv  = sel ? V1 : a1;
            int   li  = sel ? I1 : j1;
            float wv2 = sel ? a2 : V2;
            int   wi2 = sel ? j2 : I2;
            V1 = sel ? a1 : V1;
            I1 = sel ? j1 : I1;
            bool s2 = lv > wv2;
            V2 = s2 ? lv : wv2;
            I2 = s2 ? li : wi2;
        }
        amaxS[tid] = I1;
        if (V1 - V2 < TAU) {
            int k = atomicAdd(&flagCnt, 1);
            flagRow[k] = tid; flagA[k] = I1; flagB[k] = I2;
        }
    }
    __syncthreads();

    const int cnt = flagCnt;
    for (int fi = wid; fi < cnt; fi += 4) {
        int row = flagRow[fi], I1 = flagA[fi], I2 = flagB[fi];
        const float* e = emb + (size_t)(b * LL + row) * DD + 2 * lane;
        const float* a = atoms + (size_t)I1 * DD + 2 * lane;
        const float* c = atoms + (size_t)I2 * DD + 2 * lane;
        double p1 = (double)e[0] * a[0] + (double)e[1] * a[1];
        double p2 = (double)e[0] * c[0] + (double)e[1] * c[1];
        #pragma unroll
        for (int m = 1; m <= 32; m <<= 1) {
            p1 += __shfl_xor(p1, m);
            p2 += __shfl_xor(p2, m);
        }
        if (lane == 0) {
            double s1 = p1 * invn64[I1];
            double s2 = p2 * invn64[I2];
            if (s2 > s1 || (s2 == s1 && I2 < I1)) amaxS[row] = I2;
        }
    }
    __syncthreads();

    if (tid < LL) invS[tid] = invnF[amaxS[tid]];
    __syncthreads();

    for (int idx = tid; idx < LL * DD; idx += 256) {
        int l = idx >> 7, d = idx & 127;
        assoc[idx] = atoms[(size_t)amaxS[l] * DD + d] * invS[l];
    }
    __syncthreads();

    float part[LL];
    #pragma unroll
    for (int j = 0; j < LL; j++) part[j] = 0.0f;
    for (int idx = tid; idx < LL * DD; idx += 256) {
        float v = assoc[idx];
        const float* wr = W + (size_t)idx * LL;
        #pragma unroll
        for (int j = 0; j < LL; j++) part[j] = fmaf(v, wr[j], part[j]);
    }
    #pragma unroll
    for (int off = 32; off; off >>= 1) {
        #pragma unroll
        for (int j = 0; j < LL; j++) part[j] += __shfl_down(part[j], off);
    }
    if (lane == 0) {
        #pragma unroll
        for (int j = 0; j < LL; j++) wsum[wid][j] = part[j];
    }
    __syncthreads();
    if (tid < LL)
        attS[tid] = b_att[tid] + wsum[0][tid] + wsum[1][tid] + wsum[2][tid] + wsum[3][tid];
    __syncthreads();

    float o = 0.0f;
    if (tid < DD) {
        #pragma unroll
        for (int l = 0; l < LL; l++) o = fmaf(attS[l], assoc[l * DD + tid], o);
    }
    float sq = (tid < DD) ? o * o : 0.0f;
    #pragma unroll
    for (int off = 32; off; off >>= 1) sq += __shfl_xor(sq, off);
    if (lane == 0) sqw[wid] = sq;
    __syncthreads();
    float tot = sqw[0] + sqw[1] + sqw[2] + sqw[3];
    float n = sqrtf(tot);
    float inv = 1.0f / fmaxf(n, 1e-12f);
    if (tid < DD) out[(size_t)b * DD + tid] = o * inv;
}

// ---------------------------------------------------------------- launcher
extern "C" void kernel_launch(void* const* d_in, const int* in_sizes, int n_in,
                              void* d_out, int out_size, void* d_ws, size_t ws_size,
                              hipStream_t stream) {
    const float* emb   = (const float*)d_in[0];
    const float* atoms = (const float*)d_in[1];
    const float* W     = (const float*)d_in[2];
    const float* b_att = (const float*)d_in[3];
    float* out = (float*)d_out;

    char* ws = (char*)d_ws;
    uint4*  embA_hi  = (uint4*)(ws + OFF_EMBA_HI);
    uint4*  embA_lo  = (uint4*)(ws + OFF_EMBA_LO);
    uint4*  atomB_hi = (uint4*)(ws + OFF_ATOMB_HI);
    uint4*  atomB_lo = (uint4*)(ws + OFF_ATOMB_LO);
    float*  pv1      = (float*)(ws + OFF_PV1);
    float*  pv2      = (float*)(ws + OFF_PV2);
    int*    pi1      = (int*)(ws + OFF_PI1);
    int*    pi2      = (int*)(ws + OFF_PI2);
    double* invn64   = (double*)(ws + OFF_INVN64);
    float*  invnF    = (float*)(ws + OFF_INVNF);

    k_prep<<<RTILES + ATILES, 256, 0, stream>>>(emb, atoms, invn64, invnF,
                                                embA_hi, embA_lo, atomB_hi, atomB_lo);
    k_score<<<(RTILES / 16) * NSPLIT, 256, 0, stream>>>((const bf16x8*)embA_hi, (const bf16x8*)embA_lo,
                                                        atomB_hi, atomB_lo,
                                                        pv1, pv2, pi1, pi2);
    k_epilogue<<<BB, 256, 0, stream>>>(pv1, pv2, pi1, pi2,
                                       emb, atoms, invn64, invnF, W, b_att, out);
}

// Round 7
// 220.056 us; speedup vs baseline: 5.0173x; 1.2226x over previous
//
#include <hip/hip_runtime.h>
#include <math.h>

#define BB 1024
#define LL 34
#define DD 128
#define AA 4096
#define NROWS (BB * LL)        // 34816
#define RTILES (NROWS / 16)    // 2176 row tiles
#define ATILES (AA / 16)       // 256 atom tiles
#define NSPLIT 8
#define TPS (ATILES / NSPLIT)  // 32 tiles per split
#define NCHUNK (TPS / 2)       // 16 chunks of 2 tiles
#define TAU 5e-3f
#define LOSCALE 1024.0f
#define INVLOSCALE 0.0009765625f

typedef _Float16 f16;
typedef _Float16 f16x8 __attribute__((ext_vector_type(8)));
typedef float f32x4  __attribute__((ext_vector_type(4)));

// ---- ws layout (bytes), total ~15.5 MB ----
#define OFF_EMBA     0u           // RTILES*4096 = 8,912,896 (f16 hi frags)
#define OFF_ATOMB_HI 8912896u     // 1,048,576
#define OFF_ATOMB_LO 9961472u     // 1,048,576 (f16 lo * 1024)
#define OFF_PQ       11010048u    // NROWS*NSPLIT*16 = 4,456,448
#define OFF_INVN64   15466496u    // 32768
#define OFF_INVNF    15499264u    // 16384

// ---------------------------------------------------------------- k_prep
// Fused: normalize atoms (fp64 norms) + swizzle emb (f16 hi only) and
// atoms_n (f16 hi + f16 lo*1024) into MFMA-fragment-linear arrays.
__global__ __launch_bounds__(256) void k_prep(const float* __restrict__ emb,
                                              const float* __restrict__ atoms,
                                              double* __restrict__ invn64,
                                              float* __restrict__ invnF,
                                              f16x8* __restrict__ embA,
                                              f16x8* __restrict__ atomB_hi,
                                              f16x8* __restrict__ atomB_lo) {
    __shared__ double part[16][17];
    const int bid = blockIdx.x;
    const int ks = threadIdx.x >> 6, l = threadIdx.x & 63;
    const int m = l & 15, koff = ((l >> 4) << 3) + (ks << 5);

    if (bid < RTILES) {                         // embedding tile: hi only
        int tile = bid;
        const float* p = emb + (size_t)(tile * 16 + m) * DD + koff;
        float4 f0 = ((const float4*)p)[0];
        float4 f1 = ((const float4*)p)[1];
        float xs[8] = {f0.x, f0.y, f0.z, f0.w, f1.x, f1.y, f1.z, f1.w};
        f16x8 h;
        #pragma unroll
        for (int j = 0; j < 8; j++) h[j] = (f16)xs[j];
        embA[(size_t)(tile * 4 + ks) * 64 + l] = h;
    } else {                                    // atom tile: normalize + hi/lo
        int tile = bid - RTILES;
        const float* p = atoms + (size_t)(tile * 16 + m) * DD + koff;
        float4 f0 = ((const float4*)p)[0];
        float4 f1 = ((const float4*)p)[1];
        float xs[8] = {f0.x, f0.y, f0.z, f0.w, f1.x, f1.y, f1.z, f1.w};
        double ssq = 0.0;
        #pragma unroll
        for (int j = 0; j < 8; j++) ssq += (double)xs[j] * xs[j];
        part[m][ks * 4 + (l >> 4)] = ssq;
        __syncthreads();
        double tot = 0.0;
        #pragma unroll
        for (int q = 0; q < 16; q++) tot += part[m][q];
        double n = sqrt(tot);
        if (n < 1e-12) n = 1e-12;
        double inv = 1.0 / n;
        float invf = (float)inv;
        f16x8 h, lo;
        #pragma unroll
        for (int j = 0; j < 8; j++) {
            float x = xs[j] * invf;
            f16 hh = (f16)x;
            h[j] = hh;
            lo[j] = (f16)((x - (float)hh) * LOSCALE);
        }
        if (ks == 0 && (l >> 4) == 0) {
            invn64[tile * 16 + m] = inv;
            invnF[tile * 16 + m] = invf;
        }
        size_t idx = (size_t)(tile * 4 + ks) * 64 + l;
        atomB_hi[idx] = h;
        atomB_lo[idx] = lo;
    }
}

// ---------------------------------------------------------------- k_score
// 2-pass split-f16 MFMA scoring: score = hi_e*hi_a + (hi_e*(lo_a*1024))/1024.
// R=4 row-tiles per wave. B hi+lo LDS-shared across 4 waves via
// global_load_lds(16B), double-buffered 2-tile chunks. Top-2 via packed keys
// (low 5 mantissa bits = local tile id) with med3/max updates.
__global__ __launch_bounds__(256, 2) void k_score(const f16x8* __restrict__ embA,
                                                  const char* __restrict__ atomB_hi,
                                                  const char* __restrict__ atomB_lo,
                                                  float4* __restrict__ pq) {
    __shared__ __align__(16) char sbuf[2][16384];  // per buf: [0,8K)=hi, [8K,16K)=lo

    const int tid = threadIdx.x;
    const int w = tid >> 6, l = tid & 63;
    const int rb = blockIdx.x >> 3, sp = blockIdx.x & 7;
    const int rt0 = rb * 16 + w * 4;

    f16x8 a[4][4];
    #pragma unroll
    for (int f = 0; f < 4; f++)
        #pragma unroll
        for (int ks = 0; ks < 4; ks++)
            a[f][ks] = embA[(size_t)((rt0 + f) * 4 + ks) * 64 + l];

    float v1[16], v2[16];
    #pragma unroll
    for (int s = 0; s < 16; s++) { v1[s] = -3e38f; v2[s] = -3e38f; }

    #define STAGE(C, BUF)                                                          \
        {                                                                          \
            size_t _tb = (size_t)(sp * TPS + (C) * 2) * 4096;                      \
            _Pragma("unroll")                                                      \
            for (int r = 0; r < 4; r++) {                                          \
                const char* _src = (r < 2) ? (atomB_hi + _tb + r * 4096)           \
                                           : (atomB_lo + _tb + (r - 2) * 4096);    \
                uint32_t* _dst = (uint32_t*)(&sbuf[BUF][0] + r * 4096 + w * 1024); \
                __builtin_amdgcn_global_load_lds((const uint32_t*)(_src + tid * 16), \
                                                 _dst, 16, 0, 0);                  \
            }                                                                      \
        }

    STAGE(0, 0);
    __syncthreads();

    for (int c = 0; c < NCHUNK; c++) {
        const int buf = c & 1;
        if (c + 1 < NCHUNK) STAGE(c + 1, buf ^ 1);

        #pragma unroll
        for (int tt = 0; tt < 2; tt++) {
            f16x8 bh[4], bl[4];
            #pragma unroll
            for (int ks = 0; ks < 4; ks++) {
                bh[ks] = *(const f16x8*)(&sbuf[buf][0] + tt * 4096 + ks * 1024 + l * 16);
                bl[ks] = *(const f16x8*)(&sbuf[buf][0] + 8192 + tt * 4096 + ks * 1024 + l * 16);
            }
            f32x4 acc[4], accL[4];
            #pragma unroll
            for (int f = 0; f < 4; f++) {
                acc[f]  = (f32x4){0.f, 0.f, 0.f, 0.f};
                accL[f] = (f32x4){0.f, 0.f, 0.f, 0.f};
            }
            #pragma unroll
            for (int ks = 0; ks < 4; ks++) {
                #pragma unroll
                for (int f = 0; f < 4; f++) {
                    acc[f]  = __builtin_amdgcn_mfma_f32_16x16x32_f16(a[f][ks], bh[ks], acc[f],  0, 0, 0);
                    accL[f] = __builtin_amdgcn_mfma_f32_16x16x32_f16(a[f][ks], bl[ks], accL[f], 0, 0, 0);
                }
            }
            const unsigned tl = (unsigned)(c * 2 + tt);   // 0..31
            #pragma unroll
            for (int f = 0; f < 4; f++) {
                #pragma unroll
                for (int r = 0; r < 4; r++) {
                    int s = f * 4 + r;
                    float x = fmaf(accL[f][r], INVLOSCALE, acc[f][r]);
                    float xq = __uint_as_float((__float_as_uint(x) & 0xFFFFFFE0u) | tl);
                    v2[s] = __builtin_amdgcn_fmed3f(xq, v1[s], v2[s]);
                    v1[s] = fmaxf(v1[s], xq);
                }
            }
        }
        __syncthreads();
    }
    #undef STAGE

    // unpack keys -> (value, global atom index)
    float vv1[16], vv2[16];
    int jj1[16], jj2[16];
    const int col = l & 15;
    #pragma unroll
    for (int s = 0; s < 16; s++) {
        unsigned u1 = __float_as_uint(v1[s]);
        unsigned u2 = __float_as_uint(v2[s]);
        vv1[s] = __uint_as_float(u1 & 0xFFFFFFE0u);
        vv2[s] = __uint_as_float(u2 & 0xFFFFFFE0u);
        jj1[s] = (sp * TPS + (int)(u1 & 31u)) * 16 + col;
        jj2[s] = (sp * TPS + (int)(u2 & 31u)) * 16 + col;
    }

    // butterfly across the 16 lanes of each quad-group (disjoint atom sets)
    #pragma unroll
    for (int m = 1; m <= 8; m <<= 1) {
        #pragma unroll
        for (int s = 0; s < 16; s++) {
            float ov1 = __shfl_xor(vv1[s], m);
            float ov2 = __shfl_xor(vv2[s], m);
            int   oi1 = __shfl_xor(jj1[s], m);
            int   oi2 = __shfl_xor(jj2[s], m);
            bool sel = ov1 > vv1[s];
            float lv  = sel ? vv1[s] : ov1;
            int   li  = sel ? jj1[s] : oi1;
            float wv2 = sel ? ov2 : vv2[s];
            int   wi2 = sel ? oi2 : jj2[s];
            vv1[s] = sel ? ov1 : vv1[s];
            jj1[s] = sel ? oi1 : jj1[s];
            bool s2 = lv > wv2;
            vv2[s] = s2 ? lv : wv2;
            jj2[s] = s2 ? li : wi2;
        }
    }

    if ((l & 15) == 0) {
        int q = l >> 4;
        #pragma unroll
        for (int f = 0; f < 4; f++)
            #pragma unroll
            for (int r = 0; r < 4; r++) {
                int s = f * 4 + r;
                int row = (rt0 + f) * 16 + q * 4 + r;
                float4 o;
                o.x = vv1[s];
                o.y = vv2[s];
                o.z = __int_as_float(jj1[s]);
                o.w = __int_as_float(jj2[s]);
                pq[(size_t)row * NSPLIT + sp] = o;
            }
    }
}

// ---------------------------------------------------------------- k_epilogue
// Fused: merge 8-split top-2 (contiguous float4 reads), fp64 rescore of
// near-ties, gather assoc (= atoms * invnF), att = assoc_flat @ W + b via
// LDS-staged coalesced W strips, out = normalize(att @ assoc).
__global__ __launch_bounds__(256) void k_epilogue(const float4* __restrict__ pq,
                                                  const float* __restrict__ emb,
                                                  const float* __restrict__ atoms,
                                                  const double* __restrict__ invn64,
                                                  const float* __restrict__ invnF,
                                                  const float* __restrict__ W,
                                                  const float* __restrict__ b_att,
                                                  float* __restrict__ out) {
    __shared__ __align__(16) float assoc[LL * DD];   // 17408 B
    __shared__ __align__(16) float Wlds[256 * 35];   // 35840 B
    __shared__ int   amaxS[LL];
    __shared__ float invS[LL];
    __shared__ float attS[LL];
    __shared__ float wsum[4][LL];
    __shared__ float sqw[4];
    __shared__ int   flagCnt;
    __shared__ int   flagRow[LL], flagA[LL], flagB[LL];

    const int b = blockIdx.x, tid = threadIdx.x;
    const int wid = tid >> 6, lane = tid & 63;

    if (tid == 0) flagCnt = 0;
    __syncthreads();

    if (tid < LL) {
        size_t base = (size_t)(b * LL + tid) * NSPLIT;
        float V1 = -3e38f, V2 = -3e38f;
        int I1 = 0, I2 = 0;
        #pragma unroll
        for (int sp = 0; sp < NSPLIT; sp++) {
            float4 qv = pq[base + sp];
            float a1 = qv.x, a2 = qv.y;
            int   j1 = __float_as_int(qv.z), j2 = __float_as_int(qv.w);
            bool sel = a1 > V1;
            float lv  = sel ? V1 : a1;
            int   li  = sel ? I1 : j1;
            float wv2 = sel ? a2 : V2;
            int   wi2 = sel ? j2 : I2;
            V1 = sel ? a1 : V1;
            I1 = sel ? j1 : I1;
            bool s2 = lv > wv2;
            V2 = s2 ? lv : wv2;
            I2 = s2 ? li : wi2;
        }
        amaxS[tid] = I1;
        if (V1 - V2 < TAU) {
            int k = atomicAdd(&flagCnt, 1);
            flagRow[k] = tid; flagA[k] = I1; flagB[k] = I2;
        }
    }
    __syncthreads();

    const int cnt = flagCnt;
    for (int fi = wid; fi < cnt; fi += 4) {
        int row = flagRow[fi], I1 = flagA[fi], I2 = flagB[fi];
        const float* e = emb + (size_t)(b * LL + row) * DD + 2 * lane;
        const float* a = atoms + (size_t)I1 * DD + 2 * lane;
        const float* c = atoms + (size_t)I2 * DD + 2 * lane;
        double p1 = (double)e[0] * a[0] + (double)e[1] * a[1];
        double p2 = (double)e[0] * c[0] + (double)e[1] * c[1];
        #pragma unroll
        for (int m = 1; m <= 32; m <<= 1) {
            p1 += __shfl_xor(p1, m);
            p2 += __shfl_xor(p2, m);
        }
        if (lane == 0) {
            double s1 = p1 * invn64[I1];
            double s2 = p2 * invn64[I2];
            if (s2 > s1 || (s2 == s1 && I2 < I1)) amaxS[row] = I2;
        }
    }
    __syncthreads();

    if (tid < LL) invS[tid] = invnF[amaxS[tid]];
    __syncthreads();

    for (int idx = tid; idx < LL * DD; idx += 256) {
        int l = idx >> 7, d = idx & 127;
        assoc[idx] = atoms[(size_t)amaxS[l] * DD + d] * invS[l];
    }
    __syncthreads();

    // att = assoc_flat @ W via LDS-staged coalesced strips of 256 rows
    float part[LL];
    #pragma unroll
    for (int j = 0; j < LL; j++) part[j] = 0.0f;
    for (int s = 0; s < 17; s++) {
        const float* wsrc = W + (size_t)s * 256 * LL;
        #pragma unroll
        for (int i = 0; i < LL; i++) {
            int d = i * 256 + tid;
            int row = d / LL, colj = d - row * LL;
            Wlds[row * 35 + colj] = wsrc[d];
        }
        __syncthreads();
        float v = assoc[s * 256 + tid];
        #pragma unroll
        for (int j = 0; j < LL; j++)
            part[j] = fmaf(v, Wlds[tid * 35 + j], part[j]);
        __syncthreads();
    }
    #pragma unroll
    for (int off = 32; off; off >>= 1) {
        #pragma unroll
        for (int j = 0; j < LL; j++) part[j] += __shfl_down(part[j], off);
    }
    if (lane == 0) {
        #pragma unroll
        for (int j = 0; j < LL; j++) wsum[wid][j] = part[j];
    }
    __syncthreads();
    if (tid < LL)
        attS[tid] = b_att[tid] + wsum[0][tid] + wsum[1][tid] + wsum[2][tid] + wsum[3][tid];
    __syncthreads();

    float o = 0.0f;
    if (tid < DD) {
        #pragma unroll
        for (int l = 0; l < LL; l++) o = fmaf(attS[l], assoc[l * DD + tid], o);
    }
    float sq = (tid < DD) ? o * o : 0.0f;
    #pragma unroll
    for (int off = 32; off; off >>= 1) sq += __shfl_xor(sq, off);
    if (lane == 0) sqw[wid] = sq;
    __syncthreads();
    float tot = sqw[0] + sqw[1] + sqw[2] + sqw[3];
    float n = sqrtf(tot);
    float inv = 1.0f / fmaxf(n, 1e-12f);
    if (tid < DD) out[(size_t)b * DD + tid] = o * inv;
}

// ---------------------------------------------------------------- launcher
extern "C" void kernel_launch(void* const* d_in, const int* in_sizes, int n_in,
                              void* d_out, int out_size, void* d_ws, size_t ws_size,
                              hipStream_t stream) {
    const float* emb   = (const float*)d_in[0];
    const float* atoms = (const float*)d_in[1];
    const float* W     = (const float*)d_in[2];
    const float* b_att = (const float*)d_in[3];
    float* out = (float*)d_out;

    char* ws = (char*)d_ws;
    f16x8*  embA     = (f16x8*)(ws + OFF_EMBA);
    char*   atomB_hi = (char*)(ws + OFF_ATOMB_HI);
    char*   atomB_lo = (char*)(ws + OFF_ATOMB_LO);
    float4* pq       = (float4*)(ws + OFF_PQ);
    double* invn64   = (double*)(ws + OFF_INVN64);
    float*  invnF    = (float*)(ws + OFF_INVNF);

    k_prep<<<RTILES + ATILES, 256, 0, stream>>>(emb, atoms, invn64, invnF,
                                                embA, (f16x8*)atomB_hi, (f16x8*)atomB_lo);
    k_score<<<(RTILES / 16) * NSPLIT, 256, 0, stream>>>(embA, atomB_hi, atomB_lo, pq);
    k_epilogue<<<BB, 256, 0, stream>>>(pq, emb, atoms, invn64, invnF, W, b_att, out);
}

// Round 8
// 166.497 us; speedup vs baseline: 6.6313x; 1.3217x over previous
//
#include <hip/hip_runtime.h>
#include <math.h>

#define BB 1024
#define LL 34
#define DD 128
#define AA 4096
#define NROWS (BB * LL)        // 34816
#define RTILES (NROWS / 16)    // 2176 row tiles
#define ATILES (AA / 16)       // 256 atom tiles
#define NSPLIT 8
#define TPS (ATILES / NSPLIT)  // 32 tiles per split
#define NCHUNK (TPS / 4)       // 8 chunks of 4 tiles
#define TAU 2.5e-3f

typedef _Float16 f16;
typedef _Float16 f16x8 __attribute__((ext_vector_type(8)));
typedef float f32x4  __attribute__((ext_vector_type(4)));

// ---- ws layout (bytes), total ~34.9 MB ----
#define OFF_EMBA   0u            // RTILES*4096 = 8,912,896 (f16 emb frags, A-layout)
#define OFF_ATOMB  8912896u      // ATILES*4096 = 1,048,576 (f16 atoms_n frags)
#define OFF_WFRAG  9961472u      // 34*3*4*64*16 = 417,792 (f16 W frags, B-layout, N pad 48)
#define OFF_G      10379264u     // 4096*34*36*4 = 20,054,016 (G[a][l][36] fp32)
#define OFF_PQ     30433280u     // NROWS*NSPLIT*16 = 4,456,448
#define OFF_INVN64 34889728u     // 32,768
#define OFF_INVNF  34922496u     // 16,384

// ---------------------------------------------------------------- k_prep
// Three block classes: emb swizzle (f16), atom normalize+swizzle (f16, fp64
// norms), W fragment build (f16 B-layout, j padded 34->48 with zeros).
__global__ __launch_bounds__(256) void k_prep(const float* __restrict__ emb,
                                              const float* __restrict__ atoms,
                                              const float* __restrict__ W,
                                              double* __restrict__ invn64,
                                              float* __restrict__ invnF,
                                              f16x8* __restrict__ embA,
                                              f16x8* __restrict__ atomB,
                                              f16x8* __restrict__ wfrag) {
    __shared__ double part[16][17];
    const int bid = blockIdx.x;
    const int tid = threadIdx.x;

    if (bid < RTILES) {                         // embedding tile
        const int ks = tid >> 6, l = tid & 63;
        const int m = l & 15, koff = ((l >> 4) << 3) + (ks << 5);
        const float* p = emb + (size_t)(bid * 16 + m) * DD + koff;
        float4 f0 = ((const float4*)p)[0];
        float4 f1 = ((const float4*)p)[1];
        float xs[8] = {f0.x, f0.y, f0.z, f0.w, f1.x, f1.y, f1.z, f1.w};
        f16x8 h;
        #pragma unroll
        for (int j = 0; j < 8; j++) h[j] = (f16)xs[j];
        embA[(size_t)(bid * 4 + ks) * 64 + l] = h;
    } else if (bid < RTILES + ATILES) {         // atom tile: normalize + swizzle
        const int tile = bid - RTILES;
        const int ks = tid >> 6, l = tid & 63;
        const int m = l & 15, koff = ((l >> 4) << 3) + (ks << 5);
        const float* p = atoms + (size_t)(tile * 16 + m) * DD + koff;
        float4 f0 = ((const float4*)p)[0];
        float4 f1 = ((const float4*)p)[1];
        float xs[8] = {f0.x, f0.y, f0.z, f0.w, f1.x, f1.y, f1.z, f1.w};
        double ssq = 0.0;
        #pragma unroll
        for (int j = 0; j < 8; j++) ssq += (double)xs[j] * xs[j];
        part[m][ks * 4 + (l >> 4)] = ssq;
        __syncthreads();
        double tot = 0.0;
        #pragma unroll
        for (int q = 0; q < 16; q++) tot += part[m][q];
        double n = sqrt(tot);
        if (n < 1e-12) n = 1e-12;
        double inv = 1.0 / n;
        float invf = (float)inv;
        f16x8 h;
        #pragma unroll
        for (int j = 0; j < 8; j++) h[j] = (f16)(xs[j] * invf);
        if (ks == 0 && (l >> 4) == 0) {
            invn64[tile * 16 + m] = inv;
            invnF[tile * 16 + m] = invf;
        }
        atomB[(size_t)(tile * 4 + ks) * 64 + l] = h;
    } else {                                    // W fragment build: one l per block
        const int l = bid - RTILES - ATILES;    // 0..33
        for (int s = tid; s < 768; s += 256) {
            int lane = s & 63, ksnt = s >> 6;   // 0..11
            int ks = ksnt & 3, nt = ksnt >> 2;
            int j = nt * 16 + (lane & 15);
            int kb = ks * 32 + ((lane >> 4) << 3);
            f16x8 h;
            if (j < LL) {
                const float* wp = W + (size_t)(l * 128 + kb) * LL + j;
                #pragma unroll
                for (int jj = 0; jj < 8; jj++) h[jj] = (f16)wp[jj * LL];
            } else {
                #pragma unroll
                for (int jj = 0; jj < 8; jj++) h[jj] = (f16)0.f;
            }
            wfrag[(size_t)((l * 3 + nt) * 4 + ks) * 64 + lane] = h;
        }
    }
}

// ---------------------------------------------------------------- k_gtab
// G[a][l][j] = atoms_n[a] . W[l*128:..][j] via f16 MFMA; A-frags reuse atomB.
__global__ __launch_bounds__(256) void k_gtab(const f16x8* __restrict__ atomB,
                                              const f16x8* __restrict__ wfrag,
                                              float* __restrict__ G) {
    const int bid = blockIdx.x;                // 34 * 16 = 544
    const int l = bid >> 4, ag = bid & 15;
    const int w = threadIdx.x >> 6, lane = threadIdx.x & 63;

    f16x8 bw[3][4];
    #pragma unroll
    for (int nt = 0; nt < 3; nt++)
        #pragma unroll
        for (int ks = 0; ks < 4; ks++)
            bw[nt][ks] = wfrag[(size_t)((l * 3 + nt) * 4 + ks) * 64 + lane];

    const int col = lane & 15, rq = (lane >> 4) * 4;
    #pragma unroll
    for (int t = 0; t < 4; t++) {
        int atile = ag * 16 + w * 4 + t;
        f16x8 ah[4];
        #pragma unroll
        for (int ks = 0; ks < 4; ks++)
            ah[ks] = atomB[(size_t)(atile * 4 + ks) * 64 + lane];
        f32x4 acc[3];
        #pragma unroll
        for (int nt = 0; nt < 3; nt++) acc[nt] = (f32x4){0.f, 0.f, 0.f, 0.f};
        #pragma unroll
        for (int ks = 0; ks < 4; ks++)
            #pragma unroll
            for (int nt = 0; nt < 3; nt++)
                acc[nt] = __builtin_amdgcn_mfma_f32_16x16x32_f16(ah[ks], bw[nt][ks], acc[nt], 0, 0, 0);
        int a0 = atile * 16 + rq;
        #pragma unroll
        for (int nt = 0; nt < 3; nt++) {
            int j = nt * 16 + col;
            if (j < LL) {
                #pragma unroll
                for (int r = 0; r < 4; r++)
                    G[((size_t)(a0 + r) * LL + l) * 36 + j] = acc[nt][r];
            }
        }
    }
}

// ---------------------------------------------------------------- k_score
// Single-pass f16 MFMA screen. R=4 row-tiles/wave; B LDS-shared across 4
// waves via global_load_lds(16B), double-buffered 4-tile chunks. Top-2 via
// packed keys (low 5 mantissa bits = local tile id), 3 VALU/slot.
__global__ __launch_bounds__(256, 3) void k_score(const f16x8* __restrict__ embA,
                                                  const char* __restrict__ atomB,
                                                  float4* __restrict__ pq) {
    __shared__ __align__(16) char sbuf[2][16384];

    const int tid = threadIdx.x;
    const int w = tid >> 6, l = tid & 63;
    const int rb = blockIdx.x >> 3, sp = blockIdx.x & 7;
    const int rt0 = rb * 16 + w * 4;

    f16x8 a[4][4];
    #pragma unroll
    for (int f = 0; f < 4; f++)
        #pragma unroll
        for (int ks = 0; ks < 4; ks++)
            a[f][ks] = embA[(size_t)((rt0 + f) * 4 + ks) * 64 + l];

    float v1[16], v2[16];
    #pragma unroll
    for (int s = 0; s < 16; s++) { v1[s] = -3e38f; v2[s] = -3e38f; }

    #define STAGE(C, BUF)                                                          \
        {                                                                          \
            size_t _tb = (size_t)(sp * TPS + (C) * 4) * 4096;                      \
            _Pragma("unroll")                                                      \
            for (int r = 0; r < 4; r++) {                                          \
                const char* _src = atomB + _tb + r * 4096;                         \
                uint32_t* _dst = (uint32_t*)(&sbuf[BUF][0] + r * 4096 + w * 1024); \
                __builtin_amdgcn_global_load_lds((const uint32_t*)(_src + tid * 16), \
                                                 _dst, 16, 0, 0);                  \
            }                                                                      \
        }

    STAGE(0, 0);
    __syncthreads();

    for (int c = 0; c < NCHUNK; c++) {
        const int buf = c & 1;
        if (c + 1 < NCHUNK) STAGE(c + 1, buf ^ 1);

        #pragma unroll
        for (int tt = 0; tt < 4; tt++) {
            f16x8 bh[4];
            #pragma unroll
            for (int ks = 0; ks < 4; ks++)
                bh[ks] = *(const f16x8*)(&sbuf[buf][0] + tt * 4096 + ks * 1024 + l * 16);
            f32x4 acc[4];
            #pragma unroll
            for (int f = 0; f < 4; f++) acc[f] = (f32x4){0.f, 0.f, 0.f, 0.f};
            #pragma unroll
            for (int ks = 0; ks < 4; ks++)
                #pragma unroll
                for (int f = 0; f < 4; f++)
                    acc[f] = __builtin_amdgcn_mfma_f32_16x16x32_f16(a[f][ks], bh[ks], acc[f], 0, 0, 0);
            const unsigned tl = (unsigned)(c * 4 + tt);   // 0..31
            #pragma unroll
            for (int f = 0; f < 4; f++)
                #pragma unroll
                for (int r = 0; r < 4; r++) {
                    int s = f * 4 + r;
                    float xq = __uint_as_float((__float_as_uint(acc[f][r]) & 0xFFFFFFE0u) | tl);
                    v2[s] = __builtin_amdgcn_fmed3f(xq, v1[s], v2[s]);
                    v1[s] = fmaxf(v1[s], xq);
                }
        }
        __syncthreads();
    }
    #undef STAGE

    // unpack keys -> (value, global atom index)
    float vv1[16], vv2[16];
    int jj1[16], jj2[16];
    const int col = l & 15;
    #pragma unroll
    for (int s = 0; s < 16; s++) {
        unsigned u1 = __float_as_uint(v1[s]);
        unsigned u2 = __float_as_uint(v2[s]);
        vv1[s] = __uint_as_float(u1 & 0xFFFFFFE0u);
        vv2[s] = __uint_as_float(u2 & 0xFFFFFFE0u);
        jj1[s] = (sp * TPS + (int)(u1 & 31u)) * 16 + col;
        jj2[s] = (sp * TPS + (int)(u2 & 31u)) * 16 + col;
    }

    // butterfly across the 16 lanes of each quad-group (disjoint atom sets)
    #pragma unroll
    for (int m = 1; m <= 8; m <<= 1) {
        #pragma unroll
        for (int s = 0; s < 16; s++) {
            float ov1 = __shfl_xor(vv1[s], m);
            float ov2 = __shfl_xor(vv2[s], m);
            int   oi1 = __shfl_xor(jj1[s], m);
            int   oi2 = __shfl_xor(jj2[s], m);
            bool sel = ov1 > vv1[s];
            float lv  = sel ? vv1[s] : ov1;
            int   li  = sel ? jj1[s] : oi1;
            float wv2 = sel ? ov2 : vv2[s];
            int   wi2 = sel ? oi2 : jj2[s];
            vv1[s] = sel ? ov1 : vv1[s];
            jj1[s] = sel ? oi1 : jj1[s];
            bool s2 = lv > wv2;
            vv2[s] = s2 ? lv : wv2;
            jj2[s] = s2 ? li : wi2;
        }
    }

    if ((l & 15) == 0) {
        int q = l >> 4;
        #pragma unroll
        for (int f = 0; f < 4; f++)
            #pragma unroll
            for (int r = 0; r < 4; r++) {
                int s = f * 4 + r;
                int row = (rt0 + f) * 16 + q * 4 + r;
                float4 o;
                o.x = vv1[s];
                o.y = vv2[s];
                o.z = __int_as_float(jj1[s]);
                o.w = __int_as_float(jj2[s]);
                pq[(size_t)row * NSPLIT + sp] = o;
            }
    }
}

// ---------------------------------------------------------------- k_epilogue
// Merge 8-split top-2; flagged rows: fp64 rescore of ALL 16 split candidates;
// att via G-table gather; out = normalize(att @ assoc).
__global__ __launch_bounds__(256) void k_epilogue(const float4* __restrict__ pq,
                                                  const float* __restrict__ emb,
                                                  const float* __restrict__ atoms,
                                                  const double* __restrict__ invn64,
                                                  const float* __restrict__ invnF,
                                                  const float* __restrict__ G,
                                                  const float* __restrict__ b_att,
                                                  float* __restrict__ out) {
    __shared__ __align__(16) float assoc[LL * DD];   // 17408 B
    __shared__ int   amaxS[LL];
    __shared__ float invS[LL];
    __shared__ float attS[LL];
    __shared__ float wsum[4][40];
    __shared__ float sqw[4];
    __shared__ int   flagCnt;
    __shared__ int   flagRow[LL];

    const int b = blockIdx.x, tid = threadIdx.x;
    const int wid = tid >> 6, lane = tid & 63;

    if (tid == 0) flagCnt = 0;
    __syncthreads();

    if (tid < LL) {
        size_t base = (size_t)(b * LL + tid) * NSPLIT;
        float V1 = -3e38f, V2 = -3e38f;
        int I1 = 0;
        #pragma unroll
        for (int sp = 0; sp < NSPLIT; sp++) {
            float4 qv = pq[base + sp];
            float a1 = qv.x, a2 = qv.y;
            int   j1 = __float_as_int(qv.z);
            bool sel = a1 > V1;
            float lv  = sel ? V1 : a1;
            float wv2 = sel ? a2 : V2;
            V1 = sel ? a1 : V1;
            I1 = sel ? j1 : I1;
            V2 = fmaxf(lv, wv2);
        }
        amaxS[tid] = I1;
        if (V1 - V2 < TAU) {
            int k = atomicAdd(&flagCnt, 1);
            flagRow[k] = tid;
        }
    }
    __syncthreads();

    const int cnt = flagCnt;
    for (int fi = wid; fi < cnt; fi += 4) {
        int row = flagRow[fi];
        const float2 ev = ((const float2*)(emb + (size_t)(b * LL + row) * DD))[lane];
        size_t base = (size_t)(b * LL + row) * NSPLIT;
        double bestS = -1e300;
        int bestI = 0x7fffffff;
        for (int sp = 0; sp < NSPLIT; sp++) {
            float4 qv = pq[base + sp];
            #pragma unroll
            for (int h = 0; h < 2; h++) {
                int idx = __float_as_int(h ? qv.w : qv.z);
                const float2 av = ((const float2*)(atoms + (size_t)idx * DD))[lane];
                double p = (double)ev.x * av.x + (double)ev.y * av.y;
                #pragma unroll
                for (int m = 1; m <= 32; m <<= 1) p += __shfl_xor(p, m);
                double sc = p * invn64[idx];
                if (sc > bestS || (sc == bestS && idx < bestI)) { bestS = sc; bestI = idx; }
            }
        }
        if (lane == 0) amaxS[row] = bestI;
    }
    __syncthreads();

    if (tid < LL) invS[tid] = invnF[amaxS[tid]];
    // att partials via G gather (needs amaxS only)
    if (lane < LL) {
        float ga = 0.f;
        for (int ll = wid; ll < LL; ll += 4)
            ga += G[((size_t)amaxS[ll] * LL + ll) * 36 + lane];
        wsum[wid][lane] = ga;
    }
    __syncthreads();

    for (int idx = tid; idx < LL * DD; idx += 256) {
        int ll = idx >> 7, d = idx & 127;
        assoc[idx] = atoms[(size_t)amaxS[ll] * DD + d] * invS[ll];
    }
    if (tid < LL)
        attS[tid] = b_att[tid] + wsum[0][tid] + wsum[1][tid] + wsum[2][tid] + wsum[3][tid];
    __syncthreads();

    float o = 0.0f;
    if (tid < DD) {
        #pragma unroll
        for (int ll = 0; ll < LL; ll++) o = fmaf(attS[ll], assoc[ll * DD + tid], o);
    }
    float sq = (tid < DD) ? o * o : 0.0f;
    #pragma unroll
    for (int off = 32; off; off >>= 1) sq += __shfl_xor(sq, off);
    if (lane == 0) sqw[wid] = sq;
    __syncthreads();
    float tot = sqw[0] + sqw[1] + sqw[2] + sqw[3];
    float n = sqrtf(tot);
    float inv = 1.0f / fmaxf(n, 1e-12f);
    if (tid < DD) out[(size_t)b * DD + tid] = o * inv;
}

// ---------------------------------------------------------------- launcher
extern "C" void kernel_launch(void* const* d_in, const int* in_sizes, int n_in,
                              void* d_out, int out_size, void* d_ws, size_t ws_size,
                              hipStream_t stream) {
    const float* emb   = (const float*)d_in[0];
    const float* atoms = (const float*)d_in[1];
    const float* W     = (const float*)d_in[2];
    const float* b_att = (const float*)d_in[3];
    float* out = (float*)d_out;

    char* ws = (char*)d_ws;
    f16x8*  embA   = (f16x8*)(ws + OFF_EMBA);
    char*   atomB  = (char*)(ws + OFF_ATOMB);
    f16x8*  wfrag  = (f16x8*)(ws + OFF_WFRAG);
    float*  G      = (float*)(ws + OFF_G);
    float4* pq     = (float4*)(ws + OFF_PQ);
    double* invn64 = (double*)(ws + OFF_INVN64);
    float*  invnF  = (float*)(ws + OFF_INVNF);

    k_prep<<<RTILES + ATILES + LL, 256, 0, stream>>>(emb, atoms, W, invn64, invnF,
                                                     embA, (f16x8*)atomB, wfrag);
    k_gtab<<<LL * 16, 256, 0, stream>>>((const f16x8*)atomB, wfrag, G);
    k_score<<<(RTILES / 16) * NSPLIT, 256, 0, stream>>>(embA, atomB, pq);
    k_epilogue<<<BB, 256, 0, stream>>>(pq, emb, atoms, invn64, invnF, G, b_att, out);
}

// Round 10
// 157.612 us; speedup vs baseline: 7.0051x; 1.0564x over previous
//
#include <hip/hip_runtime.h>
#include <math.h>

#define BB 1024
#define LL 34
#define DD 128
#define AA 4096
#define NROWS (BB * LL)        // 34816
#define RTILES (NROWS / 16)    // 2176 row tiles
#define ATILES (AA / 16)       // 256 atom tiles
#define NSPLIT 8
#define TPS (ATILES / NSPLIT)  // 32 tiles per split
#define NCHUNK (TPS / 4)       // 8 chunks of 4 tiles
#define TAU 2.5e-3f
#define SCOREBLKS ((RTILES / 16) * NSPLIT)   // 1088
#define GTABBLKS (LL * 32)                   // 1088

typedef _Float16 f16;
typedef _Float16 f16x8 __attribute__((ext_vector_type(8)));
typedef float f32x4  __attribute__((ext_vector_type(4)));

// ---- ws layout (bytes), total ~34.9 MB ----
#define OFF_EMBA   0u            // RTILES*4096 (f16 emb frags, A-layout)
#define OFF_ATOMB  8912896u      // ATILES*4096 (f16 atoms_n frags)
#define OFF_WFRAG  9961472u      // 34*3*4*64*16 (f16 W frags, B-layout, N pad 48)
#define OFF_G      10379264u     // 34*4096*36*4 = 20,054,016  (G[l][a][36] fp32)
#define OFF_PQ     30433280u     // NROWS*NSPLIT*16
#define OFF_INVN64 34889728u
#define OFF_INVNF  34922496u

// ---------------------------------------------------------------- k_prep
// LDS-bounced coalesced loads. Three block classes: emb swizzle, atom
// normalize+swizzle (fp64 norms), W fragment build (B-layout, j pad 34->48).
__global__ __launch_bounds__(256) void k_prep(const float* __restrict__ emb,
                                              const float* __restrict__ atoms,
                                              const float* __restrict__ W,
                                              double* __restrict__ invn64,
                                              float* __restrict__ invnF,
                                              f16x8* __restrict__ embA,
                                              f16x8* __restrict__ atomB,
                                              f16x8* __restrict__ wfrag) {
    __shared__ __align__(16) float stbuf[4608];     // 18432 B
    __shared__ double part[16][17];
    const int bid = blockIdx.x;
    const int tid = threadIdx.x;

    if (bid < RTILES + ATILES) {                    // emb or atom tile
        const bool isAtom = (bid >= RTILES);
        const int tile = isAtom ? bid - RTILES : bid;
        const float* src = (isAtom ? atoms : emb) + (size_t)tile * 2048;
        float4* st4 = (float4*)stbuf;
        for (int i = tid; i < 512; i += 256) {      // coalesced 8 KB stage
            int row = i >> 5, c4 = i & 31;
            st4[row * 33 + c4] = ((const float4*)src)[i];
        }
        __syncthreads();

        const int ks = tid >> 6, l = tid & 63;
        const int m = l & 15, koff4 = ((l >> 4) << 1) + (ks << 3);
        float4 f0 = st4[m * 33 + koff4];
        float4 f1 = st4[m * 33 + koff4 + 1];
        float xs[8] = {f0.x, f0.y, f0.z, f0.w, f1.x, f1.y, f1.z, f1.w};

        if (!isAtom) {
            f16x8 h;
            #pragma unroll
            for (int j = 0; j < 8; j++) h[j] = (f16)xs[j];
            embA[(size_t)(tile * 4 + ks) * 64 + l] = h;
        } else {
            double ssq = 0.0;
            #pragma unroll
            for (int j = 0; j < 8; j++) ssq += (double)xs[j] * xs[j];
            part[m][ks * 4 + (l >> 4)] = ssq;
            __syncthreads();
            double tot = 0.0;
            #pragma unroll
            for (int q = 0; q < 16; q++) tot += part[m][q];
            double n = sqrt(tot);
            if (n < 1e-12) n = 1e-12;
            double inv = 1.0 / n;
            float invf = (float)inv;
            f16x8 h;
            #pragma unroll
            for (int j = 0; j < 8; j++) h[j] = (f16)(xs[j] * invf);
            if (ks == 0 && (l >> 4) == 0) {
                invn64[tile * 16 + m] = inv;
                invnF[tile * 16 + m] = invf;
            }
            atomB[(size_t)(tile * 4 + ks) * 64 + l] = h;
        }
    } else {                                        // W fragment build, one l
        const int l = bid - RTILES - ATILES;        // 0..33
        const float* wsrc = W + (size_t)l * 128 * LL;
        for (int i = tid; i < 128 * LL; i += 256) { // coalesced 17.4 KB stage
            int row = i / LL, j = i - row * LL;
            stbuf[row * 35 + j] = wsrc[i];
        }
        __syncthreads();
        for (int s = tid; s < 768; s += 256) {
            int lane = s & 63, ksnt = s >> 6;
            int ks = ksnt & 3, nt = ksnt >> 2;
            int j = nt * 16 + (lane & 15);
            int kb = ks * 32 + ((lane >> 4) << 3);
            f16x8 h;
            if (j < LL) {
                #pragma unroll
                for (int jj = 0; jj < 8; jj++) h[jj] = (f16)stbuf[(kb + jj) * 35 + j];
            } else {
                #pragma unroll
                for (int jj = 0; jj < 8; jj++) h[jj] = (f16)0.f;
            }
            wfrag[(size_t)((l * 3 + nt) * 4 + ks) * 64 + lane] = h;
        }
    }
}

// ---------------------------------------------------------------- k_score
// Fused: blocks [0,1088) = f16 MFMA screen (XCD-swizzled bid = sp*136+rb so
// each XCD's embA slice is L2-resident); blocks [1088,2176) = G-table build
// (G[l][a][36], LDS-staged linear stores).
__global__ __launch_bounds__(256, 3) void k_score(const f16x8* __restrict__ embA,
                                                  const char* __restrict__ atomB,
                                                  const f16x8* __restrict__ wfrag,
                                                  float* __restrict__ G,
                                                  float4* __restrict__ pq) {
    __shared__ __align__(16) char shmem[32768];
    const int tid = threadIdx.x;
    const int w = tid >> 6, l = tid & 63;

    if (blockIdx.x >= SCOREBLKS) {
        // ---------------- gtab path: 128 atoms x one l per block
        const int gb = blockIdx.x - SCOREBLKS;
        const int ll = gb >> 5, ab = gb & 31;
        float* gs = (float*)shmem;                  // [128][36] = 18432 B

        f16x8 bw[3][4];
        #pragma unroll
        for (int nt = 0; nt < 3; nt++)
            #pragma unroll
            for (int ks = 0; ks < 4; ks++)
                bw[nt][ks] = wfrag[(size_t)((ll * 3 + nt) * 4 + ks) * 64 + l];

        const int col = l & 15, rq = (l >> 4) * 4;
        #pragma unroll
        for (int t = 0; t < 2; t++) {
            int atile = ab * 8 + w * 2 + t;
            f16x8 ah[4];
            #pragma unroll
            for (int ks = 0; ks < 4; ks++)
                ah[ks] = *(const f16x8*)(atomB + ((size_t)(atile * 4 + ks) * 64 + l) * 16);
            f32x4 acc[3];
            #pragma unroll
            for (int nt = 0; nt < 3; nt++) acc[nt] = (f32x4){0.f, 0.f, 0.f, 0.f};
            #pragma unroll
            for (int ks = 0; ks < 4; ks++)
                #pragma unroll
                for (int nt = 0; nt < 3; nt++)
                    acc[nt] = __builtin_amdgcn_mfma_f32_16x16x32_f16(ah[ks], bw[nt][ks], acc[nt], 0, 0, 0);
            int aloc0 = (w * 2 + t) * 16 + rq;
            #pragma unroll
            for (int nt = 0; nt < 3; nt++) {
                int j = nt * 16 + col;
                if (j < LL) {                       // j in [34,48) is pad — skip
                    #pragma unroll
                    for (int r = 0; r < 4; r++)
                        gs[(aloc0 + r) * 36 + j] = acc[nt][r];
                }
            }
        }
        __syncthreads();
        float* Gl = G + ((size_t)ll * 4096 + ab * 128) * 36;
        for (int i = tid; i < 128 * 36; i += 256) Gl[i] = gs[i];   // linear
        return;
    }

    // ---------------- score path
    char (*sbuf)[16384] = (char(*)[16384])shmem;
    const int sp = blockIdx.x / 136, rb = blockIdx.x - sp * 136;
    const int rt0 = rb * 16 + w * 4;

    f16x8 a[4][4];
    #pragma unroll
    for (int f = 0; f < 4; f++)
        #pragma unroll
        for (int ks = 0; ks < 4; ks++)
            a[f][ks] = embA[(size_t)((rt0 + f) * 4 + ks) * 64 + l];

    float v1[16], v2[16];
    #pragma unroll
    for (int s = 0; s < 16; s++) { v1[s] = -3e38f; v2[s] = -3e38f; }

    #define STAGE(C, BUF)                                                          \
        {                                                                          \
            size_t _tb = (size_t)(sp * TPS + (C) * 4) * 4096;                      \
            _Pragma("unroll")                                                      \
            for (int r = 0; r < 4; r++) {                                          \
                const char* _src = atomB + _tb + r * 4096;                         \
                uint32_t* _dst = (uint32_t*)(&sbuf[BUF][0] + r * 4096 + w * 1024); \
                __builtin_amdgcn_global_load_lds((const uint32_t*)(_src + tid * 16), \
                                                 _dst, 16, 0, 0);                  \
            }                                                                      \
        }

    STAGE(0, 0);
    __syncthreads();

    for (int c = 0; c < NCHUNK; c++) {
        const int buf = c & 1;
        if (c + 1 < NCHUNK) STAGE(c + 1, buf ^ 1);

        #pragma unroll
        for (int tt = 0; tt < 4; tt++) {
            f16x8 bh[4];
            #pragma unroll
            for (int ks = 0; ks < 4; ks++)
                bh[ks] = *(const f16x8*)(&sbuf[buf][0] + tt * 4096 + ks * 1024 + l * 16);
            f32x4 acc[4];
            #pragma unroll
            for (int f = 0; f < 4; f++) acc[f] = (f32x4){0.f, 0.f, 0.f, 0.f};
            #pragma unroll
            for (int ks = 0; ks < 4; ks++)
                #pragma unroll
                for (int f = 0; f < 4; f++)
                    acc[f] = __builtin_amdgcn_mfma_f32_16x16x32_f16(a[f][ks], bh[ks], acc[f], 0, 0, 0);
            const unsigned tl = (unsigned)(c * 4 + tt);   // 0..31
            #pragma unroll
            for (int f = 0; f < 4; f++)
                #pragma unroll
                for (int r = 0; r < 4; r++) {
                    int s = f * 4 + r;
                    float xq = __uint_as_float((__float_as_uint(acc[f][r]) & 0xFFFFFFE0u) | tl);
                    v2[s] = __builtin_amdgcn_fmed3f(xq, v1[s], v2[s]);
                    v1[s] = fmaxf(v1[s], xq);
                }
        }
        __syncthreads();
    }
    #undef STAGE

    float vv1[16], vv2[16];
    int jj1[16], jj2[16];
    const int col = l & 15;
    #pragma unroll
    for (int s = 0; s < 16; s++) {
        unsigned u1 = __float_as_uint(v1[s]);
        unsigned u2 = __float_as_uint(v2[s]);
        vv1[s] = __uint_as_float(u1 & 0xFFFFFFE0u);
        vv2[s] = __uint_as_float(u2 & 0xFFFFFFE0u);
        jj1[s] = (sp * TPS + (int)(u1 & 31u)) * 16 + col;
        jj2[s] = (sp * TPS + (int)(u2 & 31u)) * 16 + col;
    }

    #pragma unroll
    for (int m = 1; m <= 8; m <<= 1) {
        #pragma unroll
        for (int s = 0; s < 16; s++) {
            float ov1 = __shfl_xor(vv1[s], m);
            float ov2 = __shfl_xor(vv2[s], m);
            int   oi1 = __shfl_xor(jj1[s], m);
            int   oi2 = __shfl_xor(jj2[s], m);
            bool sel = ov1 > vv1[s];
            float lv  = sel ? vv1[s] : ov1;
            int   li  = sel ? jj1[s] : oi1;
            float wv2 = sel ? ov2 : vv2[s];
            int   wi2 = sel ? oi2 : jj2[s];
            vv1[s] = sel ? ov1 : vv1[s];
            jj1[s] = sel ? oi1 : jj1[s];
            bool s2 = lv > wv2;
            vv2[s] = s2 ? lv : wv2;
            jj2[s] = s2 ? li : wi2;
        }
    }

    if ((l & 15) == 0) {
        int q = l >> 4;
        #pragma unroll
        for (int f = 0; f < 4; f++)
            #pragma unroll
            for (int r = 0; r < 4; r++) {
                int s = f * 4 + r;
                int row = (rt0 + f) * 16 + q * 4 + r;
                float4 o;
                o.x = vv1[s];
                o.y = vv2[s];
                o.z = __int_as_float(jj1[s]);
                o.w = __int_as_float(jj2[s]);
                pq[(size_t)row * NSPLIT + sp] = o;
            }
    }
}

// ---------------------------------------------------------------- k_epilogue
// Merge 8-split top-2 (LDS-preloaded pq, FULL 272-slot coverage); flagged
// rows: fp64 rescore of all 16 split candidates; att via G gather;
// out = normalize(att @ assoc).
__global__ __launch_bounds__(256) void k_epilogue(const float4* __restrict__ pq,
                                                  const float* __restrict__ emb,
                                                  const float* __restrict__ atoms,
                                                  const double* __restrict__ invn64,
                                                  const float* __restrict__ invnF,
                                                  const float* __restrict__ G,
                                                  const float* __restrict__ b_att,
                                                  float* __restrict__ out) {
    __shared__ __align__(16) float assoc[LL * DD];
    __shared__ __align__(16) float4 pqS[LL][NSPLIT];
    __shared__ int   amaxS[LL];
    __shared__ float invS[LL];
    __shared__ float attS[LL];
    __shared__ float wsum[4][40];
    __shared__ float sqw[4];
    __shared__ int   flagCnt;
    __shared__ int   flagRow[LL];

    const int b = blockIdx.x, tid = threadIdx.x;
    const int wid = tid >> 6, lane = tid & 63;

    if (tid == 0) flagCnt = 0;
    for (int i = tid; i < LL * NSPLIT; i += 256)     // 272 slots — loop, not if
        pqS[i >> 3][i & 7] = pq[(size_t)(b * LL + (i >> 3)) * NSPLIT + (i & 7)];
    __syncthreads();

    if (tid < LL) {
        float V1 = -3e38f, V2 = -3e38f;
        int I1 = 0;
        #pragma unroll
        for (int sp = 0; sp < NSPLIT; sp++) {
            float4 qv = pqS[tid][sp];
            float a1 = qv.x, a2 = qv.y;
            int   j1 = __float_as_int(qv.z);
            bool sel = a1 > V1;
            float lv  = sel ? V1 : a1;
            float wv2 = sel ? a2 : V2;
            V1 = sel ? a1 : V1;
            I1 = sel ? j1 : I1;
            V2 = fmaxf(lv, wv2);
        }
        amaxS[tid] = I1;
        if (V1 - V2 < TAU) {
            int k = atomicAdd(&flagCnt, 1);
            flagRow[k] = tid;
        }
    }
    __syncthreads();

    const int cnt = flagCnt;
    for (int fi = wid; fi < cnt; fi += 4) {
        int row = flagRow[fi];
        const float2 ev = ((const float2*)(emb + (size_t)(b * LL + row) * DD))[lane];
        double bestS = -1e300;
        int bestI = 0x7fffffff;
        for (int sp = 0; sp < NSPLIT; sp++) {
            float4 qv = pqS[row][sp];
            #pragma unroll
            for (int h = 0; h < 2; h++) {
                int idx = __float_as_int(h ? qv.w : qv.z);
                const float2 av = ((const float2*)(atoms + (size_t)idx * DD))[lane];
                double p = (double)ev.x * av.x + (double)ev.y * av.y;
                #pragma unroll
                for (int m = 1; m <= 32; m <<= 1) p += __shfl_xor(p, m);
                double sc = p * invn64[idx];
                if (sc > bestS || (sc == bestS && idx < bestI)) { bestS = sc; bestI = idx; }
            }
        }
        if (lane == 0) amaxS[row] = bestI;
    }
    __syncthreads();

    if (tid < LL) invS[tid] = invnF[amaxS[tid]];
    if (lane < LL) {
        float ga = 0.f;
        for (int ll = wid; ll < LL; ll += 4)
            ga += G[((size_t)ll * 4096 + amaxS[ll]) * 36 + lane];
        wsum[wid][lane] = ga;
    }
    __syncthreads();

    for (int idx = tid; idx < LL * DD; idx += 256) {
        int ll = idx >> 7, d = idx & 127;
        assoc[idx] = atoms[(size_t)amaxS[ll] * DD + d] * invS[ll];
    }
    if (tid < LL)
        attS[tid] = b_att[tid] + wsum[0][tid] + wsum[1][tid] + wsum[2][tid] + wsum[3][tid];
    __syncthreads();

    float o = 0.0f;
    if (tid < DD) {
        #pragma unroll
        for (int ll = 0; ll < LL; ll++) o = fmaf(attS[ll], assoc[ll * DD + tid], o);
    }
    float sq = (tid < DD) ? o * o : 0.0f;
    #pragma unroll
    for (int off = 32; off; off >>= 1) sq += __shfl_xor(sq, off);
    if (lane == 0) sqw[wid] = sq;
    __syncthreads();
    float tot = sqw[0] + sqw[1] + sqw[2] + sqw[3];
    float n = sqrtf(tot);
    float inv = 1.0f / fmaxf(n, 1e-12f);
    if (tid < DD) out[(size_t)b * DD + tid] = o * inv;
}

// ---------------------------------------------------------------- launcher
extern "C" void kernel_launch(void* const* d_in, const int* in_sizes, int n_in,
                              void* d_out, int out_size, void* d_ws, size_t ws_size,
                              hipStream_t stream) {
    const float* emb   = (const float*)d_in[0];
    const float* atoms = (const float*)d_in[1];
    const float* W     = (const float*)d_in[2];
    const float* b_att = (const float*)d_in[3];
    float* out = (float*)d_out;

    char* ws = (char*)d_ws;
    f16x8*  embA   = (f16x8*)(ws + OFF_EMBA);
    char*   atomB  = (char*)(ws + OFF_ATOMB);
    f16x8*  wfrag  = (f16x8*)(ws + OFF_WFRAG);
    float*  G      = (float*)(ws + OFF_G);
    float4* pq     = (float4*)(ws + OFF_PQ);
    double* invn64 = (double*)(ws + OFF_INVN64);
    float*  invnF  = (float*)(ws + OFF_INVNF);

    k_prep<<<RTILES + ATILES + LL, 256, 0, stream>>>(emb, atoms, W, invn64, invnF,
                                                     embA, (f16x8*)atomB, wfrag);
    k_score<<<SCOREBLKS + GTABBLKS, 256, 0, stream>>>(embA, atomB, wfrag, G, pq);
    k_epilogue<<<BB, 256, 0, stream>>>(pq, emb, atoms, invn64, invnF, G, b_att, out);
}

// Round 11
// 153.486 us; speedup vs baseline: 7.1934x; 1.0269x over previous
//
#include <hip/hip_runtime.h>
#include <math.h>

#define BB 1024
#define LL 34
#define DD 128
#define AA 4096
#define NROWS (BB * LL)        // 34816
#define RTILES (NROWS / 16)    // 2176 row tiles
#define ATILES (AA / 16)       // 256 atom tiles
#define NSPLIT 8
#define TPS (ATILES / NSPLIT)  // 32 tiles per split
#define TAU 2.5e-3f
#define SCOREBLKS ((RTILES / 16) * NSPLIT)   // 1088
#define GTABBLKS (LL * 32)                   // 1088

typedef _Float16 f16;
typedef _Float16 f16x8 __attribute__((ext_vector_type(8)));
typedef float f32x4  __attribute__((ext_vector_type(4)));

// ---- ws layout (bytes), total ~34.9 MB ----
#define OFF_EMBA   0u            // RTILES*4096 (f16 emb frags, A-layout)
#define OFF_ATOMB  8912896u      // ATILES*4096 (f16 atoms_n frags)
#define OFF_WFRAG  9961472u      // 34*3*4*64*16 (f16 W frags, B-layout, N pad 48)
#define OFF_G      10379264u     // 34*4096*36*4 = 20,054,016  (G[l][a][36] fp32)
#define OFF_PQ     30433280u     // NROWS*NSPLIT*16
#define OFF_INVN64 34889728u
#define OFF_INVNF  34922496u

// ---------------------------------------------------------------- k_prep
// LDS-bounced coalesced loads. Three block classes: emb swizzle, atom
// normalize+swizzle (fp64 norms), W fragment build (B-layout, j pad 34->48).
__global__ __launch_bounds__(256) void k_prep(const float* __restrict__ emb,
                                              const float* __restrict__ atoms,
                                              const float* __restrict__ W,
                                              double* __restrict__ invn64,
                                              float* __restrict__ invnF,
                                              f16x8* __restrict__ embA,
                                              f16x8* __restrict__ atomB,
                                              f16x8* __restrict__ wfrag) {
    __shared__ __align__(16) float stbuf[4608];     // 18432 B
    __shared__ double part[16][17];
    const int bid = blockIdx.x;
    const int tid = threadIdx.x;

    if (bid < RTILES + ATILES) {                    // emb or atom tile
        const bool isAtom = (bid >= RTILES);
        const int tile = isAtom ? bid - RTILES : bid;
        const float* src = (isAtom ? atoms : emb) + (size_t)tile * 2048;
        float4* st4 = (float4*)stbuf;
        for (int i = tid; i < 512; i += 256) {      // coalesced 8 KB stage
            int row = i >> 5, c4 = i & 31;
            st4[row * 33 + c4] = ((const float4*)src)[i];
        }
        __syncthreads();

        const int ks = tid >> 6, l = tid & 63;
        const int m = l & 15, koff4 = ((l >> 4) << 1) + (ks << 3);
        float4 f0 = st4[m * 33 + koff4];
        float4 f1 = st4[m * 33 + koff4 + 1];
        float xs[8] = {f0.x, f0.y, f0.z, f0.w, f1.x, f1.y, f1.z, f1.w};

        if (!isAtom) {
            f16x8 h;
            #pragma unroll
            for (int j = 0; j < 8; j++) h[j] = (f16)xs[j];
            embA[(size_t)(tile * 4 + ks) * 64 + l] = h;
        } else {
            double ssq = 0.0;
            #pragma unroll
            for (int j = 0; j < 8; j++) ssq += (double)xs[j] * xs[j];
            part[m][ks * 4 + (l >> 4)] = ssq;
            __syncthreads();
            double tot = 0.0;
            #pragma unroll
            for (int q = 0; q < 16; q++) tot += part[m][q];
            double n = sqrt(tot);
            if (n < 1e-12) n = 1e-12;
            double inv = 1.0 / n;
            float invf = (float)inv;
            f16x8 h;
            #pragma unroll
            for (int j = 0; j < 8; j++) h[j] = (f16)(xs[j] * invf);
            if (ks == 0 && (l >> 4) == 0) {
                invn64[tile * 16 + m] = inv;
                invnF[tile * 16 + m] = invf;
            }
            atomB[(size_t)(tile * 4 + ks) * 64 + l] = h;
        }
    } else {                                        // W fragment build, one l
        const int l = bid - RTILES - ATILES;        // 0..33
        const float* wsrc = W + (size_t)l * 128 * LL;
        for (int i = tid; i < 128 * LL; i += 256) { // coalesced 17.4 KB stage
            int row = i / LL, j = i - row * LL;
            stbuf[row * 35 + j] = wsrc[i];
        }
        __syncthreads();
        for (int s = tid; s < 768; s += 256) {
            int lane = s & 63, ksnt = s >> 6;
            int ks = ksnt & 3, nt = ksnt >> 2;
            int j = nt * 16 + (lane & 15);
            int kb = ks * 32 + ((lane >> 4) << 3);
            f16x8 h;
            if (j < LL) {
                #pragma unroll
                for (int jj = 0; jj < 8; jj++) h[jj] = (f16)stbuf[(kb + jj) * 35 + j];
            } else {
                #pragma unroll
                for (int jj = 0; jj < 8; jj++) h[jj] = (f16)0.f;
            }
            wfrag[(size_t)((l * 3 + nt) * 4 + ks) * 64 + lane] = h;
        }
    }
}

// ---------------------------------------------------------------- k_score
// Fused: blocks [0,1088) = f16 MFMA screen — BARRIER-FREE: B fragments are
// streamed L2->registers per wave with depth-1 double-buffer prefetch
// (atomB = 1 MB, L2-resident per XCD thanks to bid = sp*136+rb swizzle,
// 136%8==0 so all splits of one rb share an XCD). Blocks [1088,2176) =
// G-table build (G[l][a][36], LDS-staged linear stores).
__global__ __launch_bounds__(256, 3) void k_score(const f16x8* __restrict__ embA,
                                                  const char* __restrict__ atomB,
                                                  const f16x8* __restrict__ wfrag,
                                                  float* __restrict__ G,
                                                  float4* __restrict__ pq) {
    const int tid = threadIdx.x;
    const int w = tid >> 6, l = tid & 63;

    if (blockIdx.x >= SCOREBLKS) {
        // ---------------- gtab path: 128 atoms x one l per block
        __shared__ __align__(16) float gs[128 * 36];   // 18432 B
        const int gb = blockIdx.x - SCOREBLKS;
        const int ll = gb >> 5, ab = gb & 31;

        f16x8 bw[3][4];
        #pragma unroll
        for (int nt = 0; nt < 3; nt++)
            #pragma unroll
            for (int ks = 0; ks < 4; ks++)
                bw[nt][ks] = wfrag[(size_t)((ll * 3 + nt) * 4 + ks) * 64 + l];

        const int col = l & 15, rq = (l >> 4) * 4;
        #pragma unroll
        for (int t = 0; t < 2; t++) {
            int atile = ab * 8 + w * 2 + t;
            f16x8 ah[4];
            #pragma unroll
            for (int ks = 0; ks < 4; ks++)
                ah[ks] = *(const f16x8*)(atomB + ((size_t)(atile * 4 + ks) * 64 + l) * 16);
            f32x4 acc[3];
            #pragma unroll
            for (int nt = 0; nt < 3; nt++) acc[nt] = (f32x4){0.f, 0.f, 0.f, 0.f};
            #pragma unroll
            for (int ks = 0; ks < 4; ks++)
                #pragma unroll
                for (int nt = 0; nt < 3; nt++)
                    acc[nt] = __builtin_amdgcn_mfma_f32_16x16x32_f16(ah[ks], bw[nt][ks], acc[nt], 0, 0, 0);
            int aloc0 = (w * 2 + t) * 16 + rq;
            #pragma unroll
            for (int nt = 0; nt < 3; nt++) {
                int j = nt * 16 + col;
                if (j < LL) {                       // j in [34,48) is pad — skip
                    #pragma unroll
                    for (int r = 0; r < 4; r++)
                        gs[(aloc0 + r) * 36 + j] = acc[nt][r];
                }
            }
        }
        __syncthreads();
        float* Gl = G + ((size_t)ll * 4096 + ab * 128) * 36;
        for (int i = tid; i < 128 * 36; i += 256) Gl[i] = gs[i];   // linear
        return;
    }

    // ---------------- score path (no LDS, no __syncthreads)
    const int sp = blockIdx.x / 136, rb = blockIdx.x - sp * 136;
    const int rt0 = rb * 16 + w * 4;

    f16x8 a[4][4];
    #pragma unroll
    for (int f = 0; f < 4; f++)
        #pragma unroll
        for (int ks = 0; ks < 4; ks++)
            a[f][ks] = embA[(size_t)((rt0 + f) * 4 + ks) * 64 + l];

    float v1[16], v2[16];
    #pragma unroll
    for (int s = 0; s < 16; s++) { v1[s] = -3e38f; v2[s] = -3e38f; }

    // B frags for split sp: tile t, ks, lane -> bbase[t*256 + ks*64 + l]
    const f16x8* bbase = (const f16x8*)(atomB) + (size_t)sp * TPS * 256;

    #define LOADT(BUF, T)                                            \
        {                                                            \
            _Pragma("unroll")                                        \
            for (int ks = 0; ks < 4; ks++)                           \
                BUF[ks] = bbase[(size_t)(T) * 256 + ks * 64 + l];    \
        }

    #define COMP(BUF, T)                                                          \
        {                                                                         \
            f32x4 acc[4];                                                         \
            _Pragma("unroll")                                                     \
            for (int f = 0; f < 4; f++) acc[f] = (f32x4){0.f, 0.f, 0.f, 0.f};     \
            _Pragma("unroll")                                                     \
            for (int ks = 0; ks < 4; ks++)                                        \
                _Pragma("unroll")                                                 \
                for (int f = 0; f < 4; f++)                                       \
                    acc[f] = __builtin_amdgcn_mfma_f32_16x16x32_f16(a[f][ks], BUF[ks], acc[f], 0, 0, 0); \
            const unsigned tl = (unsigned)(T);                                    \
            _Pragma("unroll")                                                     \
            for (int f = 0; f < 4; f++)                                           \
                _Pragma("unroll")                                                 \
                for (int r = 0; r < 4; r++) {                                     \
                    int s = f * 4 + r;                                            \
                    float xq = __uint_as_float((__float_as_uint(acc[f][r]) & 0xFFFFFFE0u) | tl); \
                    v2[s] = __builtin_amdgcn_fmed3f(xq, v1[s], v2[s]);            \
                    v1[s] = fmaxf(v1[s], xq);                                     \
                }                                                                 \
        }

    f16x8 c0[4], c1[4];
    LOADT(c0, 0);
    for (int t = 0; t < TPS; t += 2) {
        LOADT(c1, t + 1);
        COMP(c0, t);
        if (t + 2 < TPS) LOADT(c0, t + 2);
        COMP(c1, t + 1);
    }
    #undef LOADT
    #undef COMP

    float vv1[16], vv2[16];
    int jj1[16], jj2[16];
    const int col = l & 15;
    #pragma unroll
    for (int s = 0; s < 16; s++) {
        unsigned u1 = __float_as_uint(v1[s]);
        unsigned u2 = __float_as_uint(v2[s]);
        vv1[s] = __uint_as_float(u1 & 0xFFFFFFE0u);
        vv2[s] = __uint_as_float(u2 & 0xFFFFFFE0u);
        jj1[s] = (sp * TPS + (int)(u1 & 31u)) * 16 + col;
        jj2[s] = (sp * TPS + (int)(u2 & 31u)) * 16 + col;
    }

    #pragma unroll
    for (int m = 1; m <= 8; m <<= 1) {
        #pragma unroll
        for (int s = 0; s < 16; s++) {
            float ov1 = __shfl_xor(vv1[s], m);
            float ov2 = __shfl_xor(vv2[s], m);
            int   oi1 = __shfl_xor(jj1[s], m);
            int   oi2 = __shfl_xor(jj2[s], m);
            bool sel = ov1 > vv1[s];
            float lv  = sel ? vv1[s] : ov1;
            int   li  = sel ? jj1[s] : oi1;
            float wv2 = sel ? ov2 : vv2[s];
            int   wi2 = sel ? oi2 : jj2[s];
            vv1[s] = sel ? ov1 : vv1[s];
            jj1[s] = sel ? oi1 : jj1[s];
            bool s2 = lv > wv2;
            vv2[s] = s2 ? lv : wv2;
            jj2[s] = s2 ? li : wi2;
        }
    }

    if ((l & 15) == 0) {
        int q = l >> 4;
        #pragma unroll
        for (int f = 0; f < 4; f++)
            #pragma unroll
            for (int r = 0; r < 4; r++) {
                int s = f * 4 + r;
                int row = (rt0 + f) * 16 + q * 4 + r;
                float4 o;
                o.x = vv1[s];
                o.y = vv2[s];
                o.z = __int_as_float(jj1[s]);
                o.w = __int_as_float(jj2[s]);
                pq[(size_t)row * NSPLIT + sp] = o;
            }
    }
}

// ---------------------------------------------------------------- k_epilogue
// Merge 8-split top-2 (LDS-preloaded pq, full 272-slot coverage); flagged
// rows: fp64 rescore of all 16 split candidates; att via G gather;
// out = normalize(att @ assoc).
__global__ __launch_bounds__(256) void k_epilogue(const float4* __restrict__ pq,
                                                  const float* __restrict__ emb,
                                                  const float* __restrict__ atoms,
                                                  const double* __restrict__ invn64,
                                                  const float* __restrict__ invnF,
                                                  const float* __restrict__ G,
                                                  const float* __restrict__ b_att,
                                                  float* __restrict__ out) {
    __shared__ __align__(16) float assoc[LL * DD];
    __shared__ __align__(16) float4 pqS[LL][NSPLIT];
    __shared__ int   amaxS[LL];
    __shared__ float invS[LL];
    __shared__ float attS[LL];
    __shared__ float wsum[4][40];
    __shared__ float sqw[4];
    __shared__ int   flagCnt;
    __shared__ int   flagRow[LL];

    const int b = blockIdx.x, tid = threadIdx.x;
    const int wid = tid >> 6, lane = tid & 63;

    if (tid == 0) flagCnt = 0;
    for (int i = tid; i < LL * NSPLIT; i += 256)     // 272 slots — loop, not if
        pqS[i >> 3][i & 7] = pq[(size_t)(b * LL + (i >> 3)) * NSPLIT + (i & 7)];
    __syncthreads();

    if (tid < LL) {
        float V1 = -3e38f, V2 = -3e38f;
        int I1 = 0;
        #pragma unroll
        for (int sp = 0; sp < NSPLIT; sp++) {
            float4 qv = pqS[tid][sp];
            float a1 = qv.x, a2 = qv.y;
            int   j1 = __float_as_int(qv.z);
            bool sel = a1 > V1;
            float lv  = sel ? V1 : a1;
            float wv2 = sel ? a2 : V2;
            V1 = sel ? a1 : V1;
            I1 = sel ? j1 : I1;
            V2 = fmaxf(lv, wv2);
        }
        amaxS[tid] = I1;
        if (V1 - V2 < TAU) {
            int k = atomicAdd(&flagCnt, 1);
            flagRow[k] = tid;
        }
    }
    __syncthreads();

    const int cnt = flagCnt;
    for (int fi = wid; fi < cnt; fi += 4) {
        int row = flagRow[fi];
        const float2 ev = ((const float2*)(emb + (size_t)(b * LL + row) * DD))[lane];
        double bestS = -1e300;
        int bestI = 0x7fffffff;
        for (int sp = 0; sp < NSPLIT; sp++) {
            float4 qv = pqS[row][sp];
            #pragma unroll
            for (int h = 0; h < 2; h++) {
                int idx = __float_as_int(h ? qv.w : qv.z);
                const float2 av = ((const float2*)(atoms + (size_t)idx * DD))[lane];
                double p = (double)ev.x * av.x + (double)ev.y * av.y;
                #pragma unroll
                for (int m = 1; m <= 32; m <<= 1) p += __shfl_xor(p, m);
                double sc = p * invn64[idx];
                if (sc > bestS || (sc == bestS && idx < bestI)) { bestS = sc; bestI = idx; }
            }
        }
        if (lane == 0) amaxS[row] = bestI;
    }
    __syncthreads();

    if (tid < LL) invS[tid] = invnF[amaxS[tid]];
    if (lane < LL) {
        float ga = 0.f;
        for (int ll = wid; ll < LL; ll += 4)
            ga += G[((size_t)ll * 4096 + amaxS[ll]) * 36 + lane];
        wsum[wid][lane] = ga;
    }
    __syncthreads();

    for (int idx = tid; idx < LL * DD; idx += 256) {
        int ll = idx >> 7, d = idx & 127;
        assoc[idx] = atoms[(size_t)amaxS[ll] * DD + d] * invS[ll];
    }
    if (tid < LL)
        attS[tid] = b_att[tid] + wsum[0][tid] + wsum[1][tid] + wsum[2][tid] + wsum[3][tid];
    __syncthreads();

    float o = 0.0f;
    if (tid < DD) {
        #pragma unroll
        for (int ll = 0; ll < LL; ll++) o = fmaf(attS[ll], assoc[ll * DD + tid], o);
    }
    float sq = (tid < DD) ? o * o : 0.0f;
    #pragma unroll
    for (int off = 32; off; off >>= 1) sq += __shfl_xor(sq, off);
    if (lane == 0) sqw[wid] = sq;
    __syncthreads();
    float tot = sqw[0] + sqw[1] + sqw[2] + sqw[3];
    float n = sqrtf(tot);
    float inv = 1.0f / fmaxf(n, 1e-12f);
    if (tid < DD) out[(size_t)b * DD + tid] = o * inv;
}

// ---------------------------------------------------------------- launcher
extern "C" void kernel_launch(void* const* d_in, const int* in_sizes, int n_in,
                              void* d_out, int out_size, void* d_ws, size_t ws_size,
                              hipStream_t stream) {
    const float* emb   = (const float*)d_in[0];
    const float* atoms = (const float*)d_in[1];
    const float* W     = (const float*)d_in[2];
    const float* b_att = (const float*)d_in[3];
    float* out = (float*)d_out;

    char* ws = (char*)d_ws;
    f16x8*  embA   = (f16x8*)(ws + OFF_EMBA);
    char*   atomB  = (char*)(ws + OFF_ATOMB);
    f16x8*  wfrag  = (f16x8*)(ws + OFF_WFRAG);
    float*  G      = (float*)(ws + OFF_G);
    float4* pq     = (float4*)(ws + OFF_PQ);
    double* invn64 = (double*)(ws + OFF_INVN64);
    float*  invnF  = (float*)(ws + OFF_INVNF);

    k_prep<<<RTILES + ATILES + LL, 256, 0, stream>>>(emb, atoms, W, invn64, invnF,
                                                     embA, (f16x8*)atomB, wfrag);
    k_score<<<SCOREBLKS + GTABBLKS, 256, 0, stream>>>(embA, atomB, wfrag, G, pq);
    k_epilogue<<<BB, 256, 0, stream>>>(pq, emb, atoms, invn64, invnF, G, b_att, out);
}